// Round 7
// baseline (1941.614 us; speedup 1.0000x reference)
//
#include <hip/hip_runtime.h>
#include <cmath>

#define BATCH 16
#define SEQ 512
#define DMODEL 512
#define NDEPTH 4
#define NHEADS 8
#define DHEAD 64
#define DFF 2048
#define CBD 64
#define CBS 8192
#define MROWS (BATCH * SEQ) // 8192

typedef unsigned short u16;
typedef __attribute__((ext_vector_type(8))) short short8; // 8 bf16 = 4 VGPRs (MFMA A/B frag)
typedef __attribute__((ext_vector_type(4))) float f32x4;  // MFMA C/D frag
typedef __attribute__((ext_vector_type(4))) unsigned short u16x4;

// attention LDS strides (bank-conflict-free: see round-6 notes)
#define SC_STRIDE 516   // fp32 words per score row (4*516%32=16 -> 2-way, free)
#define P_STRIDE  552   // u16 per P row (276 words, step%32=20 -> 2-way, free)

// ---------------------------------------------------------------- bf16 helpers
__device__ __forceinline__ u16 f2bf(float f) {
    unsigned u = __float_as_uint(f);
    u += 0x7fff + ((u >> 16) & 1); // RNE
    return (u16)(u >> 16);
}
__device__ __forceinline__ float bf2f(u16 h) {
    return __uint_as_float(((unsigned)h) << 16);
}

// async global->LDS 16B: LDS dest must be wave-uniform base + lane*16
__device__ __forceinline__ void async16(u16* lds, const u16* g) {
    __builtin_amdgcn_global_load_lds(
        (const __attribute__((address_space(1))) unsigned int*)g,
        (__attribute__((address_space(3))) unsigned int*)lds, 16, 0, 0);
}

// gelu(u) = 0.5u(1+tanh(y)) = u*sigmoid(2y) — exp-form, __expf -> v_exp_f32
__device__ __forceinline__ float gelu_tanh(float u) {
    float t = fmaf(0.07135481627f * u, u * u, 1.5957691216f * u);
    return u / (1.0f + __expf(-t));
}

// ---------------------------------------------------------------- zero output
__global__ void zero_kernel(float* __restrict__ p, int n) {
    int i = blockIdx.x * 256 + threadIdx.x;
    if (i < n) p[i] = 0.0f;
}

// ------------------------------------------------------------- codebook norms
__global__ void cbn_kernel(const float* __restrict__ cb, float* __restrict__ cbn) {
    int c = blockIdx.x * 256 + threadIdx.x;
    if (c >= CBS) return;
    const float* row = cb + (size_t)c * CBD;
    float s = 0.0f;
#pragma unroll
    for (int d = 0; d < CBD; ++d) s += row[d] * row[d];
    cbn[c] = s;
}

// ------------------------- weight transpose + split: W [z][K][N] -> T [z][N][K]
__global__ __launch_bounds__(256) void wtrans_kernel(
    const float* __restrict__ W, u16* __restrict__ Th, u16* __restrict__ Tl,
    int K, int N, long inLS, long outLS) {
    __shared__ float t[32][33];
    const float* Ws = W + (size_t)blockIdx.z * inLS;
    u16* Tho = Th + (size_t)blockIdx.z * outLS;
    u16* Tlo = Tl + (size_t)blockIdx.z * outLS;
    int n0 = blockIdx.x * 32, k0 = blockIdx.y * 32;
    int tx = threadIdx.x & 31, ty = threadIdx.x >> 5;
#pragma unroll
    for (int r = ty; r < 32; r += 8) t[r][tx] = Ws[(size_t)(k0 + r) * N + n0 + tx];
    __syncthreads();
#pragma unroll
    for (int r = ty; r < 32; r += 8) {
        float v = t[tx][r];
        size_t o = (size_t)(n0 + r) * K + k0 + tx;
        u16 hh = f2bf(v);
        Tho[o] = hh;
        Tlo[o] = f2bf(v - bf2f(hh));
    }
}

// ---------------- V transpose: head-major qkv slot [16+h][M][64] -> VT [b][d][s]
__global__ __launch_bounds__(256) void vtrans_kernel(
    const u16* __restrict__ Qh, const u16* __restrict__ Ql,
    u16* __restrict__ VTh, u16* __restrict__ VTl) {
    __shared__ u16 t[64][68];
    int s0 = blockIdx.x * 64;       // seq tile
    int hh = blockIdx.y;            // head
    int b = blockIdx.z & 15, plane = blockIdx.z >> 4;
    const u16* src = (plane ? Ql : Qh) + ((size_t)(16 + hh) * MROWS) * 64;
    u16* dst = (plane ? VTl : VTh);
    int tid = threadIdx.x;
    int rr = tid >> 4, c4 = (tid & 15) * 4;
#pragma unroll
    for (int i = 0; i < 4; ++i) {
        int r = rr + i * 16; // seq within tile
        const u16* p = src + (size_t)(b * SEQ + s0 + r) * 64 + c4;
        *(u16x4*)(&t[r][c4]) = *(const u16x4*)p;
    }
    __syncthreads();
#pragma unroll
    for (int i = 0; i < 4; ++i) {
        int r = rr + i * 16; // d-index within head
        u16x4 v;
        v.x = t[c4 + 0][r]; v.y = t[c4 + 1][r]; v.z = t[c4 + 2][r]; v.w = t[c4 + 3][r];
        *(u16x4*)(dst + (size_t)b * SEQ * DMODEL + (size_t)(hh * 64 + r) * SEQ + s0 + c4) = v;
    }
}

// ------------------------------------------------ elementwise fp32 -> (hi,lo)
__global__ void split_kernel(const float* __restrict__ X, u16* __restrict__ H,
                             u16* __restrict__ L, int n) {
    int i = blockIdx.x * 256 + threadIdx.x;
    if (i < n) {
        float v = X[i];
        u16 hh = f2bf(v);
        H[i] = hh;
        L[i] = f2bf(v - bf2f(hh));
    }
}

// ---------------------------------------- layernorm (+split-K reduce folding)
__global__ __launch_bounds__(256) void ln_kernel(
    const float* __restrict__ X,
    const float* __restrict__ C0, const float* __restrict__ C1,
    const float* __restrict__ bias2, const float* __restrict__ pos2,
    float* __restrict__ Xout,
    float* __restrict__ Y, u16* __restrict__ Yh, u16* __restrict__ Yl,
    const float* __restrict__ g, const float* __restrict__ b) {
    int row  = blockIdx.x * 4 + (threadIdx.x >> 6);
    int lane = threadIdx.x & 63;
    float v[8];
    float s = 0.0f;
#pragma unroll
    for (int j = 0; j < 8; ++j) {
        int d = lane + j * 64;
        size_t o = (size_t)row * DMODEL + d;
        float t = X ? X[o] : 0.0f;
        if (C0)    t += C0[o] + C1[o];
        if (bias2) t += bias2[d];
        if (pos2)  t += pos2[(size_t)(row & (SEQ - 1)) * DMODEL + d];
        v[j] = t;
        if (Xout) Xout[o] = t;
        s += t;
    }
#pragma unroll
    for (int off = 32; off; off >>= 1) s += __shfl_xor(s, off);
    float mu  = s * (1.0f / DMODEL);
    float var = 0.0f;
#pragma unroll
    for (int j = 0; j < 8; ++j) { float d = v[j] - mu; var += d * d; }
#pragma unroll
    for (int off = 32; off; off >>= 1) var += __shfl_xor(var, off);
    float r = rsqrtf(var * (1.0f / DMODEL) + 1e-5f);
#pragma unroll
    for (int j = 0; j < 8; ++j) {
        int d = lane + j * 64;
        float y = (v[j] - mu) * r * g[d] + b[d];
        size_t o = (size_t)row * DMODEL + d;
        if (Y) Y[o] = y;
        if (Yh) {
            u16 hh = f2bf(y);
            Yh[o] = hh;
            Yl[o] = f2bf(y - bf2f(hh));
        }
    }
}

// --------------------------------------------------------- bf16x3 MFMA GEMM
// Fused single K-loop (48 MFMA per barrier-pair). kslice>0: split-K partials.
// qkvscatter: store C head-major — o = ((n>>6)*M + m)*64 + (n&63).
__global__ __launch_bounds__(256) void gemm3_kernel(
    const u16* __restrict__ Ah, const u16* __restrict__ Al,
    const u16* __restrict__ Bh, const u16* __restrict__ Bl,
    float* __restrict__ Cf, u16* __restrict__ Ch, u16* __restrict__ Cl,
    const float* __restrict__ bias, const float* __restrict__ res,
    const float* __restrict__ pos, int M, int N, int K, int gelu,
    float* __restrict__ Cs0, float* __restrict__ Cs1, int kslice, int qkvscatter) {
    __shared__ __align__(16) u16 AsH[128 * 32];
    __shared__ __align__(16) u16 AsL[128 * 32];
    __shared__ __align__(16) u16 BsH[128 * 32];
    __shared__ __align__(16) u16 BsL[128 * 32];

    int tid  = threadIdx.x;
    int w    = tid >> 6, lane = tid & 63;
    int wr   = w >> 1, wc = w & 1;
    int quad = lane >> 4, l16 = lane & 15;
    int m0   = blockIdx.x * 128;
    int n0   = blockIdx.y * 128;
    int ksA  = (kslice > 0) ? blockIdx.z * kslice : 0;
    int ksB  = (kslice > 0) ? ksA + kslice : K;

    f32x4 acc[4][4];
#pragma unroll
    for (int i = 0; i < 4; ++i)
#pragma unroll
        for (int j = 0; j < 4; ++j) acc[i][j] = (f32x4){0.f, 0.f, 0.f, 0.f};

    int off0 = tid * 16;
    int row0s = off0 >> 6, ke0 = (off0 & 63) >> 1;
    int off1 = 4096 + tid * 16;
    int row1s = off1 >> 6, ke1 = (off1 & 63) >> 1;

    const u16* AbaseH = Ah + (size_t)m0 * K;
    const u16* AbaseL = Al + (size_t)m0 * K;
    const u16* BbaseH = Bh + (size_t)n0 * K;
    const u16* BbaseL = Bl + (size_t)n0 * K;

    for (int ks = ksA; ks < ksB; ks += 32) {
        __syncthreads();
        async16(&AsH[off0 >> 1], AbaseH + (size_t)row0s * K + ks + ke0);
        async16(&AsH[off1 >> 1], AbaseH + (size_t)row1s * K + ks + ke1);
        async16(&AsL[off0 >> 1], AbaseL + (size_t)row0s * K + ks + ke0);
        async16(&AsL[off1 >> 1], AbaseL + (size_t)row1s * K + ks + ke1);
        async16(&BsH[off0 >> 1], BbaseH + (size_t)row0s * K + ks + ke0);
        async16(&BsH[off1 >> 1], BbaseH + (size_t)row1s * K + ks + ke1);
        async16(&BsL[off0 >> 1], BbaseL + (size_t)row0s * K + ks + ke0);
        async16(&BsL[off1 >> 1], BbaseL + (size_t)row1s * K + ks + ke1);
        __syncthreads();
        short8 afh[4], afl[4];
#pragma unroll
        for (int i = 0; i < 4; ++i) {
            afh[i] = *(const short8*)&AsH[(wr * 64 + i * 16 + l16) * 32 + quad * 8];
            afl[i] = *(const short8*)&AsL[(wr * 64 + i * 16 + l16) * 32 + quad * 8];
        }
#pragma unroll
        for (int j = 0; j < 4; ++j) {
            short8 bh = *(const short8*)&BsH[(wc * 64 + j * 16 + l16) * 32 + quad * 8];
            short8 bl = *(const short8*)&BsL[(wc * 64 + j * 16 + l16) * 32 + quad * 8];
#pragma unroll
            for (int i = 0; i < 4; ++i) {
                acc[i][j] = __builtin_amdgcn_mfma_f32_16x16x32_bf16(afh[i], bh, acc[i][j], 0, 0, 0);
                acc[i][j] = __builtin_amdgcn_mfma_f32_16x16x32_bf16(afl[i], bh, acc[i][j], 0, 0, 0);
                acc[i][j] = __builtin_amdgcn_mfma_f32_16x16x32_bf16(afh[i], bl, acc[i][j], 0, 0, 0);
            }
        }
    }

    float* Cspl = (kslice > 0) ? (blockIdx.z ? Cs1 : Cs0) : nullptr;
    int mbase = m0 + wr * 64;
    int nbase = n0 + wc * 64;
#pragma unroll
    for (int mi = 0; mi < 4; ++mi)
#pragma unroll
        for (int ni = 0; ni < 4; ++ni) {
            f32x4 a = acc[mi][ni];
#pragma unroll
            for (int r = 0; r < 4; ++r) {
                int m = mbase + mi * 16 + quad * 4 + r;
                int n = nbase + ni * 16 + l16;
                float v = a[r];
                size_t o = qkvscatter
                    ? ((size_t)(n >> 6) * M + m) * 64 + (n & 63)
                    : (size_t)m * N + n;
                if (Cspl) { Cspl[o] = v; continue; }
                if (bias) v += bias[n];
                if (pos)  v += pos[(size_t)(m & (SEQ - 1)) * N + n];
                if (res)  v += res[(size_t)m * N + n];
                if (gelu) v = gelu_tanh(v);
                if (Cf) Cf[o] = v;
                if (Ch) {
                    u16 hh = f2bf(v);
                    Ch[o] = hh;
                    Cl[o] = f2bf(v - bf2f(hh));
                }
            }
        }
}

// ------------------------------------------------------------ fp32 GEMM (small)
__global__ __launch_bounds__(256) void gemm_kernel(
    const float* __restrict__ A, const float* __restrict__ Bm,
    float* __restrict__ C, const float* __restrict__ bias,
    int M, int N, int K) {
    __shared__ float As[16][68];
    __shared__ float Bs[16][64];
    int tid = threadIdx.x;
    int tx = tid & 15, ty = tid >> 4;
    int a_m = tid >> 2, a_k = (tid & 3) * 4;
    int b_k = tid >> 4, b_n = (tid & 15) * 4;
    const float* Arow = A + (size_t)(blockIdx.x * 64 + a_m) * K;
    const float* Bcol = Bm + (size_t)blockIdx.y * 64 + b_n;
    float acc[4][4] = {};
    for (int k0 = 0; k0 < K; k0 += 16) {
        float4 av = *(const float4*)(Arow + k0 + a_k);
        float4 bv = *(const float4*)(Bcol + (size_t)(k0 + b_k) * N);
        __syncthreads();
        As[a_k + 0][a_m] = av.x; As[a_k + 1][a_m] = av.y;
        As[a_k + 2][a_m] = av.z; As[a_k + 3][a_m] = av.w;
        *(float4*)(&Bs[b_k][b_n]) = bv;
        __syncthreads();
#pragma unroll
        for (int kk = 0; kk < 16; ++kk) {
            float4 a4 = *(const float4*)(&As[kk][ty * 4]);
            float4 b4 = *(const float4*)(&Bs[kk][tx * 4]);
            float ar[4] = {a4.x, a4.y, a4.z, a4.w};
            float br[4] = {b4.x, b4.y, b4.z, b4.w};
#pragma unroll
            for (int i = 0; i < 4; ++i)
#pragma unroll
                for (int j = 0; j < 4; ++j) acc[i][j] = fmaf(ar[i], br[j], acc[i][j]);
        }
    }
    int m0 = blockIdx.x * 64 + ty * 4;
    int n0 = blockIdx.y * 64 + tx * 4;
#pragma unroll
    for (int i = 0; i < 4; ++i) {
        float vv[4];
#pragma unroll
        for (int j = 0; j < 4; ++j) {
            float t = acc[i][j];
            if (bias) t += bias[n0 + j];
            vv[j] = t;
        }
        *(float4*)(C + (size_t)(m0 + i) * N + n0) = make_float4(vv[0], vv[1], vv[2], vv[3]);
    }
}

// ----------------------------------------------------------- MFMA attention
// head-major QKV planes: slot s in [0,24): Q=h, K=8+h, V=16+h; each [M][64].
__global__ __launch_bounds__(256) void attn_mfma_kernel(
    const u16* __restrict__ QKh, const u16* __restrict__ QKl,
    const u16* __restrict__ VTh, const u16* __restrict__ VTl,
    u16* __restrict__ Oh, u16* __restrict__ Ol) {
    int qt = blockIdx.x & 31;
    int hh = (blockIdx.x >> 5) & 7;
    int bb = blockIdx.x >> 8;

    __shared__ __align__(16) unsigned char ldsbuf[16 * P_STRIDE * 2 * 2]; // 35328 B
    float* sc = (float*)ldsbuf;       // [16][SC_STRIDE] fp32 (33024 B used)
    u16* Ph = (u16*)ldsbuf;           // [16][P_STRIDE]
    u16* Pl = Ph + 16 * P_STRIDE;

    int tid = threadIdx.x;
    int w = tid >> 6, lane = tid & 63;
    int quad = lane >> 4, l16 = lane & 15;

    // Q frags: head-major, row-contiguous (128B rows)
    const u16* qrh = QKh + ((size_t)hh * MROWS + bb * SEQ + qt * 16 + l16) * 64 + quad * 8;
    const u16* qrl = QKl + ((size_t)hh * MROWS + bb * SEQ + qt * 16 + l16) * 64 + quad * 8;
    short8 Qh0 = *(const short8*)qrh;
    short8 Qh1 = *(const short8*)(qrh + 32);
    short8 Ql0 = *(const short8*)qrl;
    short8 Ql1 = *(const short8*)(qrl + 32);

    for (int kt = 0; kt < 8; ++kt) {
        size_t krow = (size_t)(8 + hh) * MROWS + bb * SEQ + kt * 64 + w * 16 + l16;
        const u16* krh = QKh + krow * 64 + quad * 8;
        const u16* krl = QKl + krow * 64 + quad * 8;
        short8 Kh0 = *(const short8*)krh;
        short8 Kh1 = *(const short8*)(krh + 32);
        short8 Kl0 = *(const short8*)krl;
        short8 Kl1 = *(const short8*)(krl + 32);
        f32x4 a = (f32x4){0.f, 0.f, 0.f, 0.f};
        a = __builtin_amdgcn_mfma_f32_16x16x32_bf16(Qh0, Kh0, a, 0, 0, 0);
        a = __builtin_amdgcn_mfma_f32_16x16x32_bf16(Qh1, Kh1, a, 0, 0, 0);
        a = __builtin_amdgcn_mfma_f32_16x16x32_bf16(Ql0, Kh0, a, 0, 0, 0);
        a = __builtin_amdgcn_mfma_f32_16x16x32_bf16(Ql1, Kh1, a, 0, 0, 0);
        a = __builtin_amdgcn_mfma_f32_16x16x32_bf16(Qh0, Kl0, a, 0, 0, 0);
        a = __builtin_amdgcn_mfma_f32_16x16x32_bf16(Qh1, Kl1, a, 0, 0, 0);
        int key = kt * 64 + w * 16 + l16;
#pragma unroll
        for (int r = 0; r < 4; ++r)
            sc[(quad * 4 + r) * SC_STRIDE + key] = a[r] * 0.125f;
    }
    __syncthreads();

    float e[4][8];
#pragma unroll
    for (int rr = 0; rr < 4; ++rr) {
        int qi = w + rr * 4;
        float m = -1e30f;
#pragma unroll
        for (int j = 0; j < 8; ++j) { e[rr][j] = sc[qi * SC_STRIDE + lane + j * 64]; m = fmaxf(m, e[rr][j]); }
#pragma unroll
        for (int off = 32; off; off >>= 1) m = fmaxf(m, __shfl_xor(m, off));
        float sum = 0.0f;
#pragma unroll
        for (int j = 0; j < 8; ++j) { e[rr][j] = __expf(e[rr][j] - m); sum += e[rr][j]; }
#pragma unroll
        for (int off = 32; off; off >>= 1) sum += __shfl_xor(sum, off);
        float inv = 1.0f / sum;
#pragma unroll
        for (int j = 0; j < 8; ++j) e[rr][j] *= inv;
    }
    __syncthreads();

#pragma unroll
    for (int rr = 0; rr < 4; ++rr) {
        int qi = w + rr * 4;
#pragma unroll
        for (int j = 0; j < 8; ++j) {
            float v = e[rr][j];
            u16 hv = f2bf(v);
            Ph[qi * P_STRIDE + lane + j * 64] = hv;
            Pl[qi * P_STRIDE + lane + j * 64] = f2bf(v - bf2f(hv));
        }
    }
    __syncthreads();

    const u16* vth = VTh + ((size_t)bb * SEQ + hh * 64 + w * 16 + l16) * SEQ + quad * 8;
    const u16* vtl = VTl + ((size_t)bb * SEQ + hh * 64 + w * 16 + l16) * SEQ + quad * 8;
    const u16* ph = Ph + l16 * P_STRIDE + quad * 8;
    const u16* pl = Pl + l16 * P_STRIDE + quad * 8;
    f32x4 acc0 = (f32x4){0.f, 0.f, 0.f, 0.f};
    f32x4 acc1 = (f32x4){0.f, 0.f, 0.f, 0.f};
#pragma unroll
    for (int ks = 0; ks < 512; ks += 64) {
        short8 P0h = *(const short8*)(ph + ks);
        short8 P0l = *(const short8*)(pl + ks);
        short8 V0h = *(const short8*)(vth + ks);
        short8 V0l = *(const short8*)(vtl + ks);
        short8 P1h = *(const short8*)(ph + ks + 32);
        short8 P1l = *(const short8*)(pl + ks + 32);
        short8 V1h = *(const short8*)(vth + ks + 32);
        short8 V1l = *(const short8*)(vtl + ks + 32);
        acc0 = __builtin_amdgcn_mfma_f32_16x16x32_bf16(P0h, V0h, acc0, 0, 0, 0);
        acc1 = __builtin_amdgcn_mfma_f32_16x16x32_bf16(P1h, V1h, acc1, 0, 0, 0);
        acc0 = __builtin_amdgcn_mfma_f32_16x16x32_bf16(P0l, V0h, acc0, 0, 0, 0);
        acc1 = __builtin_amdgcn_mfma_f32_16x16x32_bf16(P1l, V1h, acc1, 0, 0, 0);
        acc0 = __builtin_amdgcn_mfma_f32_16x16x32_bf16(P0h, V0l, acc0, 0, 0, 0);
        acc1 = __builtin_amdgcn_mfma_f32_16x16x32_bf16(P1h, V1l, acc1, 0, 0, 0);
    }
    f32x4 o = acc0 + acc1;
#pragma unroll
    for (int r = 0; r < 4; ++r) {
        int q = quad * 4 + r;
        size_t off = (size_t)(bb * SEQ + qt * 16 + q) * DMODEL + hh * 64 + w * 16 + l16;
        u16 hv = f2bf(o[r]);
        Oh[off] = hv;
        Ol[off] = f2bf(o[r] - bf2f(hv));
    }
}

// ----------------------------------------------------------------- MFMA VQ
__global__ __launch_bounds__(256) void vq3_kernel(
    const float* __restrict__ Z, const u16* __restrict__ Zh, const u16* __restrict__ Zl,
    const u16* __restrict__ CBh, const u16* __restrict__ CBl,
    const float* __restrict__ CB, const float* __restrict__ CBN,
    float* __restrict__ out) {
    __shared__ float sbest[4][16];
    __shared__ int sidx[4][16];
    __shared__ int ibest[16];
    __shared__ float psum[4][64];
    __shared__ float cl4[4];

    int tid = threadIdx.x;
    int w = tid >> 6, lane = tid & 63;
    int quad = lane >> 4, l16 = lane & 15;
    int row0 = blockIdx.x * 16;

    const u16* zph = Zh + (size_t)(row0 + l16) * CBD + quad * 8;
    const u16* zpl = Zl + (size_t)(row0 + l16) * CBD + quad * 8;
    short8 Z0h = *(const short8*)zph;
    short8 Z1h = *(const short8*)(zph + 32);
    short8 Z0l = *(const short8*)zpl;
    short8 Z1l = *(const short8*)(zpl + 32);

    float best[4] = {3.4e38f, 3.4e38f, 3.4e38f, 3.4e38f};
    int bidx[4] = {0, 0, 0, 0};

    int cbase = w * (CBS / 4);
#pragma unroll 2
    for (int t = 0; t < CBS / 4; t += 16) {
        int code = cbase + t + l16;
        const u16* cph = CBh + (size_t)code * CBD + quad * 8;
        const u16* cpl = CBl + (size_t)code * CBD + quad * 8;
        short8 C0h = *(const short8*)cph;
        short8 C1h = *(const short8*)(cph + 32);
        short8 C0l = *(const short8*)cpl;
        short8 C1l = *(const short8*)(cpl + 32);
        float cn = CBN[code];
        f32x4 a = (f32x4){0.f, 0.f, 0.f, 0.f};
        a = __builtin_amdgcn_mfma_f32_16x16x32_bf16(Z0h, C0h, a, 0, 0, 0);
        a = __builtin_amdgcn_mfma_f32_16x16x32_bf16(Z1h, C1h, a, 0, 0, 0);
        a = __builtin_amdgcn_mfma_f32_16x16x32_bf16(Z0l, C0h, a, 0, 0, 0);
        a = __builtin_amdgcn_mfma_f32_16x16x32_bf16(Z1l, C1h, a, 0, 0, 0);
        a = __builtin_amdgcn_mfma_f32_16x16x32_bf16(Z0h, C0l, a, 0, 0, 0);
        a = __builtin_amdgcn_mfma_f32_16x16x32_bf16(Z1h, C1l, a, 0, 0, 0);
#pragma unroll
        for (int r = 0; r < 4; ++r) {
            float s = cn - 2.0f * a[r];
            if (s < best[r]) { best[r] = s; bidx[r] = code; }
        }
    }
#pragma unroll
    for (int off = 8; off; off >>= 1) {
#pragma unroll
        for (int r = 0; r < 4; ++r) {
            float ov = __shfl_xor(best[r], off);
            int oi = __shfl_xor(bidx[r], off);
            if (ov < best[r] || (ov == best[r] && oi < bidx[r])) { best[r] = ov; bidx[r] = oi; }
        }
    }
    if (l16 == 0) {
#pragma unroll
        for (int r = 0; r < 4; ++r) {
            sbest[w][quad * 4 + r] = best[r];
            sidx[w][quad * 4 + r] = bidx[r];
        }
    }
    __syncthreads();
    if (tid < 16) {
        float bv = sbest[0][tid];
        int bi = sidx[0][tid];
#pragma unroll
        for (int ww = 1; ww < 4; ++ww) {
            float ov = sbest[ww][tid];
            int oi = sidx[ww][tid];
            if (ov < bv || (ov == bv && oi < bi)) { bv = ov; bi = oi; }
        }
        ibest[tid] = bi;
    }
    __syncthreads();

    int d2 = lane;
    float qacc = 0.0f, closs = 0.0f;
#pragma unroll
    for (int j = 0; j < 4; ++j) {
        int r2 = w * 4 + j;
        int bi = ibest[r2];
        float q = CB[(size_t)bi * CBD + d2];
        float z = Z[(size_t)(row0 + r2) * CBD + d2];
        qacc += q;
        float df = q - z;
        closs += df * df;
    }
    psum[w][d2] = qacc;
#pragma unroll
    for (int off = 32; off; off >>= 1) closs += __shfl_xor(closs, off);
    if (d2 == 0) cl4[w] = closs;
    __syncthreads();
    if (tid < 64) {
        float t = psum[0][tid] + psum[1][tid] + psum[2][tid] + psum[3][tid];
        int b = row0 >> 9;
        atomicAdd(out + b * 64 + tid, t);
    }
    if (tid == 0)
        atomicAdd(out + 1024, (cl4[0] + cl4[1] + cl4[2] + cl4[3]) * (1.0f / (float)(MROWS * CBD)));
}

// -------------------------------------------------------------------- launch
extern "C" void kernel_launch(void* const* d_in, const int* in_sizes, int n_in,
                              void* d_out, int out_size, void* d_ws, size_t ws_size,
                              hipStream_t stream) {
    const float* x    = (const float*)d_in[0];
    const float* w_in = (const float*)d_in[1];
    const float* b_in = (const float*)d_in[2];
    const float* pos  = (const float*)d_in[3];
    const float* ln1g = (const float*)d_in[4];
    const float* ln1b = (const float*)d_in[5];
    const float* wq   = (const float*)d_in[6];
    const float* wk   = (const float*)d_in[7];
    const float* wv   = (const float*)d_in[8];
    const float* wo   = (const float*)d_in[9];
    const float* ln2g = (const float*)d_in[10];
    const float* ln2b = (const float*)d_in[11];
    const float* ffw1 = (const float*)d_in[12];
    const float* ffb1 = (const float*)d_in[13];
    const float* ffw2 = (const float*)d_in[14];
    const float* ffb2 = (const float*)d_in[15];
    const float* lnfg = (const float*)d_in[16];
    const float* lnfb = (const float*)d_in[17];
    const float* wout = (const float*)d_in[18];
    const float* bout = (const float*)d_in[19];
    const float* cb   = (const float*)d_in[20];
    float* out = (float*)d_out;

    const size_t MD  = (size_t)MROWS * DMODEL;   // 4,194,304
    const size_t MQ  = (size_t)MROWS * 1536;     // 12,582,912
    const size_t MF  = (size_t)MROWS * DFF;      // 16,777,216

    float* ws   = (float*)d_ws;
    float* h    = ws;
    float* t0   = h + MD;
    float* big  = t0 + MD;                   // MF floats (aliased region)
    float* zb   = big + MF;
    float* cbn  = zb + (size_t)MROWS * CBD;
    u16* cbh    = (u16*)(cbn + CBS);
    u16* cbl    = cbh + (size_t)CBS * CBD;
    u16* t0h    = (u16*)(cbh + 2 * (size_t)CBS * CBD);
    u16* t0l    = t0h + MD;
    u16* wb     = t0l + MD;

    // big aliases
    u16* qkvh = (u16*)big;
    u16* qkvl = qkvh + MQ;
    u16* obh  = qkvl + MQ;
    u16* obl  = obh + MD;
    u16* xh   = obh;
    u16* xl   = obl;
    u16* fmh  = (u16*)big;
    u16* fml  = fmh + MF;
    u16* zbh  = (u16*)big;        // VQ phase: big region is dead
    u16* zbl  = zbh + (size_t)MROWS * CBD;

    const size_t S_WIN  = (size_t)DMODEL * DMODEL;
    const size_t S_QKV  = (size_t)1536 * DMODEL * NDEPTH;
    const size_t S_WO   = S_WIN * NDEPTH;
    const size_t S_FF1  = (size_t)DFF * DMODEL * NDEPTH;
    const size_t S_FF2  = S_FF1;
    u16* winT_h = wb;
    u16* winT_l = winT_h + S_WIN;
    u16* qkvT_h = winT_l + S_WIN;
    u16* qkvT_l = qkvT_h + S_QKV;
    u16* woT_h  = qkvT_l + S_QKV;
    u16* woT_l  = woT_h + S_WO;
    u16* ff1T_h = woT_l + S_WO;
    u16* ff1T_l = ff1T_h + S_FF1;
    u16* ff2T_h = ff1T_l + S_FF1;
    u16* ff2T_l = ff2T_h + S_FF2;
    u16* VTh = ff2T_l + S_FF2;
    u16* VTl = VTh + (size_t)BATCH * SEQ * DMODEL;
    // split-K partial buffers (fp32, M x 512 each)
    float* spK0 = (float*)(VTl + (size_t)BATCH * SEQ * DMODEL);
    float* spK1 = spK0 + MD;

    dim3 blk(256);

    zero_kernel<<<dim3((out_size + 255) / 256), blk, 0, stream>>>(out, out_size);
    cbn_kernel<<<dim3(CBS / 256), blk, 0, stream>>>(cb, cbn);
    split_kernel<<<dim3((int)(CBS * CBD / 256)), blk, 0, stream>>>(cb, cbh, cbl, CBS * CBD);

    wtrans_kernel<<<dim3(16, 16, 1), blk, 0, stream>>>(w_in, winT_h, winT_l, DMODEL, DMODEL, 0, 0);
    wtrans_kernel<<<dim3(16, 16, NDEPTH), blk, 0, stream>>>(
        wq, qkvT_h, qkvT_l, DMODEL, DMODEL, (long)DMODEL * DMODEL, (long)1536 * DMODEL);
    wtrans_kernel<<<dim3(16, 16, NDEPTH), blk, 0, stream>>>(
        wk, qkvT_h + (size_t)512 * DMODEL, qkvT_l + (size_t)512 * DMODEL,
        DMODEL, DMODEL, (long)DMODEL * DMODEL, (long)1536 * DMODEL);
    wtrans_kernel<<<dim3(16, 16, NDEPTH), blk, 0, stream>>>(
        wv, qkvT_h + (size_t)1024 * DMODEL, qkvT_l + (size_t)1024 * DMODEL,
        DMODEL, DMODEL, (long)DMODEL * DMODEL, (long)1536 * DMODEL);
    wtrans_kernel<<<dim3(16, 16, NDEPTH), blk, 0, stream>>>(
        wo, woT_h, woT_l, DMODEL, DMODEL, (long)DMODEL * DMODEL, (long)DMODEL * DMODEL);
    wtrans_kernel<<<dim3(DFF / 32, 16, NDEPTH), blk, 0, stream>>>(
        ffw1, ff1T_h, ff1T_l, DMODEL, DFF, (long)DMODEL * DFF, (long)DFF * DMODEL);
    wtrans_kernel<<<dim3(16, DFF / 32, NDEPTH), blk, 0, stream>>>(
        ffw2, ff2T_h, ff2T_l, DFF, DMODEL, (long)DFF * DMODEL, (long)DMODEL * DFF);

    split_kernel<<<dim3((int)(MD / 256)), blk, 0, stream>>>(x, xh, xl, (int)MD);

    // input projection: split-K=2 -> spK0/spK1 (reduced+pos+bias inside ln1 of layer 0)
    gemm3_kernel<<<dim3(MROWS / 128, DMODEL / 128, 2), blk, 0, stream>>>(
        xh, xl, winT_h, winT_l, nullptr, nullptr, nullptr, nullptr, nullptr, nullptr,
        MROWS, DMODEL, DMODEL, 0, spK0, spK1, 256, 0);

    for (int l = 0; l < NDEPTH; ++l) {
        // ln1 folds: l==0 -> input proj (+b_in+pos); l>0 -> previous ff2 (+ffb2[l-1])
        ln_kernel<<<dim3(MROWS / 4), blk, 0, stream>>>(
            (l == 0) ? nullptr : h, spK0, spK1,
            (l == 0) ? b_in : (ffb2 + (size_t)(l - 1) * DMODEL),
            (l == 0) ? pos : nullptr, h,
            nullptr, t0h, t0l, ln1g + l * DMODEL, ln1b + l * DMODEL);
        // fused QKV -> head-major split planes (slot = part*8+head, each [M][64])
        gemm3_kernel<<<dim3(MROWS / 128, 1536 / 128, 1), blk, 0, stream>>>(
            t0h, t0l, qkvT_h + (size_t)l * 1536 * DMODEL, qkvT_l + (size_t)l * 1536 * DMODEL,
            nullptr, qkvh, qkvl, nullptr, nullptr, nullptr, MROWS, 1536, DMODEL, 0,
            nullptr, nullptr, 0, 1);
        vtrans_kernel<<<dim3(8, 8, 32), blk, 0, stream>>>(qkvh, qkvl, VTh, VTl);
        attn_mfma_kernel<<<dim3(BATCH * NHEADS * (SEQ / 16)), blk, 0, stream>>>(
            qkvh, qkvl, VTh, VTl, obh, obl);
        // wo: split-K=2 (reduced + residual inside ln2)
        gemm3_kernel<<<dim3(MROWS / 128, DMODEL / 128, 2), blk, 0, stream>>>(
            obh, obl, woT_h + (size_t)l * S_WIN, woT_l + (size_t)l * S_WIN,
            nullptr, nullptr, nullptr, nullptr, nullptr, nullptr,
            MROWS, DMODEL, DMODEL, 0, spK0, spK1, 256, 0);
        ln_kernel<<<dim3(MROWS / 4), blk, 0, stream>>>(
            h, spK0, spK1, nullptr, nullptr, h,
            nullptr, t0h, t0l, ln2g + l * DMODEL, ln2b + l * DMODEL);
        gemm3_kernel<<<dim3(MROWS / 128, DFF / 128, 1), blk, 0, stream>>>(
            t0h, t0l, ff1T_h + (size_t)l * DFF * DMODEL, ff1T_l + (size_t)l * DFF * DMODEL,
            nullptr, fmh, fml, ffb1 + l * DFF, nullptr, nullptr, MROWS, DFF, DMODEL, 1,
            nullptr, nullptr, 0, 0);
        // ff2: split-K=2 over K=2048 (reduced + ffb2 + residual in next ln1/lnf)
        gemm3_kernel<<<dim3(MROWS / 128, DMODEL / 128, 2), blk, 0, stream>>>(
            fmh, fml, ff2T_h + (size_t)l * DFF * DMODEL, ff2T_l + (size_t)l * DFF * DMODEL,
            nullptr, nullptr, nullptr, nullptr, nullptr, nullptr,
            MROWS, DMODEL, DFF, 0, spK0, spK1, 1024, 0);
    }

    // final ln folds last ff2 (+ffb2[3]); writes fp32 t0 for the out-projection
    ln_kernel<<<dim3(MROWS / 4), blk, 0, stream>>>(
        h, spK0, spK1, ffb2 + (size_t)3 * DMODEL, nullptr, nullptr,
        t0, nullptr, nullptr, lnfg, lnfb);
    gemm_kernel<<<dim3(MROWS / 64, 1), blk, 0, stream>>>(t0, wout, zb, bout, MROWS, CBD, DMODEL);
    split_kernel<<<dim3((int)((size_t)MROWS * CBD / 256)), blk, 0, stream>>>(
        zb, zbh, zbl, MROWS * CBD);
    vq3_kernel<<<dim3(MROWS / 16), blk, 0, stream>>>(zb, zbh, zbl, cbh, cbl, cb, cbn, out);
}

// Round 8
// 1915.408 us; speedup vs baseline: 1.0137x; 1.0137x over previous
//
#include <hip/hip_runtime.h>
#include <cmath>

#define BATCH 16
#define SEQ 512
#define DMODEL 512
#define NDEPTH 4
#define NHEADS 8
#define DHEAD 64
#define DFF 2048
#define CBD 64
#define CBS 8192
#define MROWS (BATCH * SEQ) // 8192

typedef unsigned short u16;
typedef __attribute__((ext_vector_type(8))) short short8; // 8 bf16 = 4 VGPRs (MFMA A/B frag)
typedef __attribute__((ext_vector_type(4))) float f32x4;  // MFMA C/D frag
typedef __attribute__((ext_vector_type(4))) unsigned short u16x4;

// ---------------------------------------------------------------- bf16 helpers
__device__ __forceinline__ u16 f2bf(float f) {
    unsigned u = __float_as_uint(f);
    u += 0x7fff + ((u >> 16) & 1); // RNE
    return (u16)(u >> 16);
}
__device__ __forceinline__ float bf2f(u16 h) {
    return __uint_as_float(((unsigned)h) << 16);
}

// async global->LDS 16B: LDS dest must be wave-uniform base + lane*16
__device__ __forceinline__ void async16(u16* lds, const u16* g) {
    __builtin_amdgcn_global_load_lds(
        (const __attribute__((address_space(1))) unsigned int*)g,
        (__attribute__((address_space(3))) unsigned int*)lds, 16, 0, 0);
}

// gelu(u) = 0.5u(1+tanh(y)) = u*sigmoid(2y) — exp-form, __expf -> v_exp_f32
__device__ __forceinline__ float gelu_tanh(float u) {
    float t = fmaf(0.07135481627f * u, u * u, 1.5957691216f * u);
    return u / (1.0f + __expf(-t));
}

// ---------------------------------------------------------------- zero output
__global__ void zero_kernel(float* __restrict__ p, int n) {
    int i = blockIdx.x * 256 + threadIdx.x;
    if (i < n) p[i] = 0.0f;
}

// ------------------------------------------------------------- codebook norms
__global__ void cbn_kernel(const float* __restrict__ cb, float* __restrict__ cbn) {
    int c = blockIdx.x * 256 + threadIdx.x;
    if (c >= CBS) return;
    const float* row = cb + (size_t)c * CBD;
    float s = 0.0f;
#pragma unroll
    for (int d = 0; d < CBD; ++d) s += row[d] * row[d];
    cbn[c] = s;
}

// ------------------------- weight transpose + split: W [z][K][N] -> T [z][N][K]
__global__ __launch_bounds__(256) void wtrans_kernel(
    const float* __restrict__ W, u16* __restrict__ Th, u16* __restrict__ Tl,
    int K, int N, long inLS, long outLS) {
    __shared__ float t[32][33];
    const float* Ws = W + (size_t)blockIdx.z * inLS;
    u16* Tho = Th + (size_t)blockIdx.z * outLS;
    u16* Tlo = Tl + (size_t)blockIdx.z * outLS;
    int n0 = blockIdx.x * 32, k0 = blockIdx.y * 32;
    int tx = threadIdx.x & 31, ty = threadIdx.x >> 5;
#pragma unroll
    for (int r = ty; r < 32; r += 8) t[r][tx] = Ws[(size_t)(k0 + r) * N + n0 + tx];
    __syncthreads();
#pragma unroll
    for (int r = ty; r < 32; r += 8) {
        float v = t[tx][r];
        size_t o = (size_t)(n0 + r) * K + k0 + tx;
        u16 hh = f2bf(v);
        Tho[o] = hh;
        Tlo[o] = f2bf(v - bf2f(hh));
    }
}

// ---------------- V transpose: head-major qkv slot [16+h][M][64] -> VT [b][d][s]
__global__ __launch_bounds__(256) void vtrans_kernel(
    const u16* __restrict__ Qh, const u16* __restrict__ Ql,
    u16* __restrict__ VTh, u16* __restrict__ VTl) {
    __shared__ u16 t[64][68];
    int s0 = blockIdx.x * 64;       // seq tile
    int hh = blockIdx.y;            // head
    int b = blockIdx.z & 15, plane = blockIdx.z >> 4;
    const u16* src = (plane ? Ql : Qh) + ((size_t)(16 + hh) * MROWS) * 64;
    u16* dst = (plane ? VTl : VTh);
    int tid = threadIdx.x;
    int rr = tid >> 4, c4 = (tid & 15) * 4;
#pragma unroll
    for (int i = 0; i < 4; ++i) {
        int r = rr + i * 16; // seq within tile
        const u16* p = src + (size_t)(b * SEQ + s0 + r) * 64 + c4;
        *(u16x4*)(&t[r][c4]) = *(const u16x4*)p;
    }
    __syncthreads();
#pragma unroll
    for (int i = 0; i < 4; ++i) {
        int r = rr + i * 16; // d-index within head
        u16x4 v;
        v.x = t[c4 + 0][r]; v.y = t[c4 + 1][r]; v.z = t[c4 + 2][r]; v.w = t[c4 + 3][r];
        *(u16x4*)(dst + (size_t)b * SEQ * DMODEL + (size_t)(hh * 64 + r) * SEQ + s0 + c4) = v;
    }
}

// ------------------------------------------------ elementwise fp32 -> (hi,lo)
__global__ void split_kernel(const float* __restrict__ X, u16* __restrict__ H,
                             u16* __restrict__ L, int n) {
    int i = blockIdx.x * 256 + threadIdx.x;
    if (i < n) {
        float v = X[i];
        u16 hh = f2bf(v);
        H[i] = hh;
        L[i] = f2bf(v - bf2f(hh));
    }
}

// ---------------------------------------- layernorm (+split-K reduce folding)
__global__ __launch_bounds__(256) void ln_kernel(
    const float* __restrict__ X,
    const float* __restrict__ C0, const float* __restrict__ C1,
    const float* __restrict__ bias2, const float* __restrict__ pos2,
    float* __restrict__ Xout,
    float* __restrict__ Y, u16* __restrict__ Yh, u16* __restrict__ Yl,
    const float* __restrict__ g, const float* __restrict__ b) {
    int row  = blockIdx.x * 4 + (threadIdx.x >> 6);
    int lane = threadIdx.x & 63;
    float v[8];
    float s = 0.0f;
#pragma unroll
    for (int j = 0; j < 8; ++j) {
        int d = lane + j * 64;
        size_t o = (size_t)row * DMODEL + d;
        float t = X ? X[o] : 0.0f;
        if (C0)    t += C0[o] + C1[o];
        if (bias2) t += bias2[d];
        if (pos2)  t += pos2[(size_t)(row & (SEQ - 1)) * DMODEL + d];
        v[j] = t;
        if (Xout) Xout[o] = t;
        s += t;
    }
#pragma unroll
    for (int off = 32; off; off >>= 1) s += __shfl_xor(s, off);
    float mu  = s * (1.0f / DMODEL);
    float var = 0.0f;
#pragma unroll
    for (int j = 0; j < 8; ++j) { float d = v[j] - mu; var += d * d; }
#pragma unroll
    for (int off = 32; off; off >>= 1) var += __shfl_xor(var, off);
    float r = rsqrtf(var * (1.0f / DMODEL) + 1e-5f);
#pragma unroll
    for (int j = 0; j < 8; ++j) {
        int d = lane + j * 64;
        float y = (v[j] - mu) * r * g[d] + b[d];
        size_t o = (size_t)row * DMODEL + d;
        if (Y) Y[o] = y;
        if (Yh) {
            u16 hh = f2bf(y);
            Yh[o] = hh;
            Yl[o] = f2bf(y - bf2f(hh));
        }
    }
}

// --------------------------------------------------------- bf16x3 MFMA GEMM
// Fused single K-loop (48 MFMA per barrier-pair). kslice>0: split-K partials.
// qkvscatter: store C head-major — o = ((n>>6)*M + m)*64 + (n&63).
__global__ __launch_bounds__(256) void gemm3_kernel(
    const u16* __restrict__ Ah, const u16* __restrict__ Al,
    const u16* __restrict__ Bh, const u16* __restrict__ Bl,
    float* __restrict__ Cf, u16* __restrict__ Ch, u16* __restrict__ Cl,
    const float* __restrict__ bias, const float* __restrict__ res,
    const float* __restrict__ pos, int M, int N, int K, int gelu,
    float* __restrict__ Cs0, float* __restrict__ Cs1, int kslice, int qkvscatter) {
    __shared__ __align__(16) u16 AsH[128 * 32];
    __shared__ __align__(16) u16 AsL[128 * 32];
    __shared__ __align__(16) u16 BsH[128 * 32];
    __shared__ __align__(16) u16 BsL[128 * 32];

    int tid  = threadIdx.x;
    int w    = tid >> 6, lane = tid & 63;
    int wr   = w >> 1, wc = w & 1;
    int quad = lane >> 4, l16 = lane & 15;
    int m0   = blockIdx.x * 128;
    int n0   = blockIdx.y * 128;
    int ksA  = (kslice > 0) ? blockIdx.z * kslice : 0;
    int ksB  = (kslice > 0) ? ksA + kslice : K;

    f32x4 acc[4][4];
#pragma unroll
    for (int i = 0; i < 4; ++i)
#pragma unroll
        for (int j = 0; j < 4; ++j) acc[i][j] = (f32x4){0.f, 0.f, 0.f, 0.f};

    int off0 = tid * 16;
    int row0s = off0 >> 6, ke0 = (off0 & 63) >> 1;
    int off1 = 4096 + tid * 16;
    int row1s = off1 >> 6, ke1 = (off1 & 63) >> 1;

    const u16* AbaseH = Ah + (size_t)m0 * K;
    const u16* AbaseL = Al + (size_t)m0 * K;
    const u16* BbaseH = Bh + (size_t)n0 * K;
    const u16* BbaseL = Bl + (size_t)n0 * K;

    for (int ks = ksA; ks < ksB; ks += 32) {
        __syncthreads();
        async16(&AsH[off0 >> 1], AbaseH + (size_t)row0s * K + ks + ke0);
        async16(&AsH[off1 >> 1], AbaseH + (size_t)row1s * K + ks + ke1);
        async16(&AsL[off0 >> 1], AbaseL + (size_t)row0s * K + ks + ke0);
        async16(&AsL[off1 >> 1], AbaseL + (size_t)row1s * K + ks + ke1);
        async16(&BsH[off0 >> 1], BbaseH + (size_t)row0s * K + ks + ke0);
        async16(&BsH[off1 >> 1], BbaseH + (size_t)row1s * K + ks + ke1);
        async16(&BsL[off0 >> 1], BbaseL + (size_t)row0s * K + ks + ke0);
        async16(&BsL[off1 >> 1], BbaseL + (size_t)row1s * K + ks + ke1);
        __syncthreads();
        short8 afh[4], afl[4];
#pragma unroll
        for (int i = 0; i < 4; ++i) {
            afh[i] = *(const short8*)&AsH[(wr * 64 + i * 16 + l16) * 32 + quad * 8];
            afl[i] = *(const short8*)&AsL[(wr * 64 + i * 16 + l16) * 32 + quad * 8];
        }
#pragma unroll
        for (int j = 0; j < 4; ++j) {
            short8 bh = *(const short8*)&BsH[(wc * 64 + j * 16 + l16) * 32 + quad * 8];
            short8 bl = *(const short8*)&BsL[(wc * 64 + j * 16 + l16) * 32 + quad * 8];
#pragma unroll
            for (int i = 0; i < 4; ++i) {
                acc[i][j] = __builtin_amdgcn_mfma_f32_16x16x32_bf16(afh[i], bh, acc[i][j], 0, 0, 0);
                acc[i][j] = __builtin_amdgcn_mfma_f32_16x16x32_bf16(afl[i], bh, acc[i][j], 0, 0, 0);
                acc[i][j] = __builtin_amdgcn_mfma_f32_16x16x32_bf16(afh[i], bl, acc[i][j], 0, 0, 0);
            }
        }
    }

    float* Cspl = (kslice > 0) ? (blockIdx.z ? Cs1 : Cs0) : nullptr;
    int mbase = m0 + wr * 64;
    int nbase = n0 + wc * 64;
#pragma unroll
    for (int mi = 0; mi < 4; ++mi)
#pragma unroll
        for (int ni = 0; ni < 4; ++ni) {
            f32x4 a = acc[mi][ni];
#pragma unroll
            for (int r = 0; r < 4; ++r) {
                int m = mbase + mi * 16 + quad * 4 + r;
                int n = nbase + ni * 16 + l16;
                float v = a[r];
                size_t o = qkvscatter
                    ? ((size_t)(n >> 6) * M + m) * 64 + (n & 63)
                    : (size_t)m * N + n;
                if (Cspl) { Cspl[o] = v; continue; }
                if (bias) v += bias[n];
                if (pos)  v += pos[(size_t)(m & (SEQ - 1)) * N + n];
                if (res)  v += res[(size_t)m * N + n];
                if (gelu) v = gelu_tanh(v);
                if (Cf) Cf[o] = v;
                if (Ch) {
                    u16 hh = f2bf(v);
                    Ch[o] = hh;
                    Cl[o] = f2bf(v - bf2f(hh));
                }
            }
        }
}

// ------------------------------------------------------------ fp32 GEMM (small)
__global__ __launch_bounds__(256) void gemm_kernel(
    const float* __restrict__ A, const float* __restrict__ Bm,
    float* __restrict__ C, const float* __restrict__ bias,
    int M, int N, int K) {
    __shared__ float As[16][68];
    __shared__ float Bs[16][64];
    int tid = threadIdx.x;
    int tx = tid & 15, ty = tid >> 4;
    int a_m = tid >> 2, a_k = (tid & 3) * 4;
    int b_k = tid >> 4, b_n = (tid & 15) * 4;
    const float* Arow = A + (size_t)(blockIdx.x * 64 + a_m) * K;
    const float* Bcol = Bm + (size_t)blockIdx.y * 64 + b_n;
    float acc[4][4] = {};
    for (int k0 = 0; k0 < K; k0 += 16) {
        float4 av = *(const float4*)(Arow + k0 + a_k);
        float4 bv = *(const float4*)(Bcol + (size_t)(k0 + b_k) * N);
        __syncthreads();
        As[a_k + 0][a_m] = av.x; As[a_k + 1][a_m] = av.y;
        As[a_k + 2][a_m] = av.z; As[a_k + 3][a_m] = av.w;
        *(float4*)(&Bs[b_k][b_n]) = bv;
        __syncthreads();
#pragma unroll
        for (int kk = 0; kk < 16; ++kk) {
            float4 a4 = *(const float4*)(&As[kk][ty * 4]);
            float4 b4 = *(const float4*)(&Bs[kk][tx * 4]);
            float ar[4] = {a4.x, a4.y, a4.z, a4.w};
            float br[4] = {b4.x, b4.y, b4.z, b4.w};
#pragma unroll
            for (int i = 0; i < 4; ++i)
#pragma unroll
                for (int j = 0; j < 4; ++j) acc[i][j] = fmaf(ar[i], br[j], acc[i][j]);
        }
    }
    int m0 = blockIdx.x * 64 + ty * 4;
    int n0 = blockIdx.y * 64 + tx * 4;
#pragma unroll
    for (int i = 0; i < 4; ++i) {
        float vv[4];
#pragma unroll
        for (int j = 0; j < 4; ++j) {
            float t = acc[i][j];
            if (bias) t += bias[n0 + j];
            vv[j] = t;
        }
        *(float4*)(C + (size_t)(m0 + i) * N + n0) = make_float4(vv[0], vv[1], vv[2], vv[3]);
    }
}

// ------------------------------------------- flash attention (online softmax)
// grid 1024: bh = blk&127 (same-(b,h) blocks -> same XCD), qt = blk>>7.
// block = 4 waves; wave w owns 16 queries (qtile = qt*4+w) INDEPENDENTLY:
// no __syncthreads. Per kt (64 keys): QK (24 MFMA, bf16x3), online m/l update,
// P via wave-private fp32 LDS round-trip (C->A layout), PV (24 MFMA).
// K/V re-read demand = 8 blocks per (b,h) (4x less than R7's 32).
__global__ __launch_bounds__(256) void attn_flash_kernel(
    const u16* __restrict__ QKh, const u16* __restrict__ QKl,
    const u16* __restrict__ VTh, const u16* __restrict__ VTl,
    u16* __restrict__ Oh, u16* __restrict__ Ol) {
    int bh = blockIdx.x & 127;
    int qt = blockIdx.x >> 7;   // 0..7
    int bb = bh >> 3, hh = bh & 7;

    __shared__ __align__(16) float Pw[4][16 * 68]; // wave-private P tiles (17408 B)

    int tid = threadIdx.x;
    int w = tid >> 6, lane = tid & 63;
    int quad = lane >> 4, l16 = lane & 15;
    int qtile = qt * 4 + w;     // 0..31
    float* P = Pw[w];

    // Q frags (A-layout: m=l16 -> query, k=quad*8+j -> d)
    const u16* qrh = QKh + ((size_t)hh * MROWS + bb * SEQ + qtile * 16 + l16) * 64 + quad * 8;
    const u16* qrl = QKl + ((size_t)hh * MROWS + bb * SEQ + qtile * 16 + l16) * 64 + quad * 8;
    short8 Qh0 = *(const short8*)qrh;
    short8 Qh1 = *(const short8*)(qrh + 32);
    short8 Ql0 = *(const short8*)qrl;
    short8 Ql1 = *(const short8*)(qrl + 32);

    float m[4] = {-1e30f, -1e30f, -1e30f, -1e30f};
    float lsum[4] = {0.f, 0.f, 0.f, 0.f};
    f32x4 acc[4];
#pragma unroll
    for (int dt = 0; dt < 4; ++dt) acc[dt] = (f32x4){0.f, 0.f, 0.f, 0.f};

    const u16* KbH = QKh + ((size_t)(8 + hh) * MROWS + bb * SEQ) * 64;
    const u16* KbL = QKl + ((size_t)(8 + hh) * MROWS + bb * SEQ) * 64;
    const u16* VbH = VTh + (size_t)bb * SEQ * DMODEL + (size_t)(hh * 64) * SEQ;
    const u16* VbL = VTl + (size_t)bb * SEQ * DMODEL + (size_t)(hh * 64) * SEQ;

    for (int kt = 0; kt < 8; ++kt) {
        int kb = kt * 64;
        // ---- S = QK^T for 64 keys (4 subtiles of 16)
        f32x4 st[4];
#pragma unroll
        for (int s = 0; s < 4; ++s) {
            const u16* kh = KbH + (size_t)(kb + s * 16 + l16) * 64 + quad * 8;
            const u16* kl = KbL + (size_t)(kb + s * 16 + l16) * 64 + quad * 8;
            short8 Kh0 = *(const short8*)kh;
            short8 Kh1 = *(const short8*)(kh + 32);
            short8 Kl0 = *(const short8*)kl;
            short8 Kl1 = *(const short8*)(kl + 32);
            f32x4 a = (f32x4){0.f, 0.f, 0.f, 0.f};
            a = __builtin_amdgcn_mfma_f32_16x16x32_bf16(Qh0, Kh0, a, 0, 0, 0);
            a = __builtin_amdgcn_mfma_f32_16x16x32_bf16(Qh1, Kh1, a, 0, 0, 0);
            a = __builtin_amdgcn_mfma_f32_16x16x32_bf16(Ql0, Kh0, a, 0, 0, 0);
            a = __builtin_amdgcn_mfma_f32_16x16x32_bf16(Ql1, Kh1, a, 0, 0, 0);
            a = __builtin_amdgcn_mfma_f32_16x16x32_bf16(Qh0, Kl0, a, 0, 0, 0);
            a = __builtin_amdgcn_mfma_f32_16x16x32_bf16(Qh1, Kl1, a, 0, 0, 0);
            st[s] = a * 0.125f;
        }
        // ---- online softmax: lane's rows = quad*4+r, cols = s*16+l16
        float alpha[4];
#pragma unroll
        for (int r = 0; r < 4; ++r) {
            float mx = fmaxf(fmaxf(st[0][r], st[1][r]), fmaxf(st[2][r], st[3][r]));
#pragma unroll
            for (int off = 8; off; off >>= 1) mx = fmaxf(mx, __shfl_xor(mx, off));
            float mn = fmaxf(m[r], mx);
            alpha[r] = __expf(m[r] - mn);
            m[r] = mn;
        }
#pragma unroll
        for (int r = 0; r < 4; ++r) {
            float rs = 0.f;
#pragma unroll
            for (int s = 0; s < 4; ++s) {
                float p = __expf(st[s][r] - m[r]);
                st[s][r] = p;
                rs += p;
            }
#pragma unroll
            for (int off = 8; off; off >>= 1) rs += __shfl_xor(rs, off);
            lsum[r] = lsum[r] * alpha[r] + rs;
        }
#pragma unroll
        for (int dt = 0; dt < 4; ++dt)
#pragma unroll
            for (int r = 0; r < 4; ++r) acc[dt][r] *= alpha[r];
        // ---- P: C-layout regs -> wave-private LDS (fp32) -> A-layout frags
#pragma unroll
        for (int s = 0; s < 4; ++s)
#pragma unroll
            for (int r = 0; r < 4; ++r)
                P[(quad * 4 + r) * 68 + s * 16 + l16] = st[s][r];
        short8 ph[2], pl[2];
#pragma unroll
        for (int ks = 0; ks < 2; ++ks) {
            const float* src = &P[l16 * 68 + ks * 32 + quad * 8];
            f32x4 a0 = *(const f32x4*)src;
            f32x4 a1 = *(const f32x4*)(src + 4);
            float v[8] = {a0[0], a0[1], a0[2], a0[3], a1[0], a1[1], a1[2], a1[3]};
#pragma unroll
            for (int j = 0; j < 8; ++j) {
                u16 hv = f2bf(v[j]);
                ph[ks][j] = (short)hv;
                pl[ks][j] = (short)f2bf(v[j] - bf2f(hv));
            }
        }
        // ---- O += P V (4 d-subtiles)
#pragma unroll
        for (int dt = 0; dt < 4; ++dt) {
            const u16* vh = VbH + (size_t)(dt * 16 + l16) * SEQ + kb + quad * 8;
            const u16* vl = VbL + (size_t)(dt * 16 + l16) * SEQ + kb + quad * 8;
            short8 Vh0 = *(const short8*)vh;
            short8 Vh1 = *(const short8*)(vh + 32);
            short8 Vl0 = *(const short8*)vl;
            short8 Vl1 = *(const short8*)(vl + 32);
            acc[dt] = __builtin_amdgcn_mfma_f32_16x16x32_bf16(ph[0], Vh0, acc[dt], 0, 0, 0);
            acc[dt] = __builtin_amdgcn_mfma_f32_16x16x32_bf16(ph[1], Vh1, acc[dt], 0, 0, 0);
            acc[dt] = __builtin_amdgcn_mfma_f32_16x16x32_bf16(pl[0], Vh0, acc[dt], 0, 0, 0);
            acc[dt] = __builtin_amdgcn_mfma_f32_16x16x32_bf16(pl[1], Vh1, acc[dt], 0, 0, 0);
            acc[dt] = __builtin_amdgcn_mfma_f32_16x16x32_bf16(ph[0], Vl0, acc[dt], 0, 0, 0);
            acc[dt] = __builtin_amdgcn_mfma_f32_16x16x32_bf16(ph[1], Vl1, acc[dt], 0, 0, 0);
        }
    }

    // ---- epilogue: normalize by l, write split O (row-major [M][DMODEL])
#pragma unroll
    for (int r = 0; r < 4; ++r) {
        float inv = 1.0f / lsum[r];
        size_t rowoff = (size_t)(bb * SEQ + qtile * 16 + quad * 4 + r) * DMODEL + hh * 64;
#pragma unroll
        for (int dt = 0; dt < 4; ++dt) {
            float v = acc[dt][r] * inv;
            u16 hv = f2bf(v);
            Oh[rowoff + dt * 16 + l16] = hv;
            Ol[rowoff + dt * 16 + l16] = f2bf(v - bf2f(hv));
        }
    }
}

// ----------------------------------------------------------------- MFMA VQ
__global__ __launch_bounds__(256) void vq3_kernel(
    const float* __restrict__ Z, const u16* __restrict__ Zh, const u16* __restrict__ Zl,
    const u16* __restrict__ CBh, const u16* __restrict__ CBl,
    const float* __restrict__ CB, const float* __restrict__ CBN,
    float* __restrict__ out) {
    __shared__ float sbest[4][16];
    __shared__ int sidx[4][16];
    __shared__ int ibest[16];
    __shared__ float psum[4][64];
    __shared__ float cl4[4];

    int tid = threadIdx.x;
    int w = tid >> 6, lane = tid & 63;
    int quad = lane >> 4, l16 = lane & 15;
    int row0 = blockIdx.x * 16;

    const u16* zph = Zh + (size_t)(row0 + l16) * CBD + quad * 8;
    const u16* zpl = Zl + (size_t)(row0 + l16) * CBD + quad * 8;
    short8 Z0h = *(const short8*)zph;
    short8 Z1h = *(const short8*)(zph + 32);
    short8 Z0l = *(const short8*)zpl;
    short8 Z1l = *(const short8*)(zpl + 32);

    float best[4] = {3.4e38f, 3.4e38f, 3.4e38f, 3.4e38f};
    int bidx[4] = {0, 0, 0, 0};

    int cbase = w * (CBS / 4);
#pragma unroll 2
    for (int t = 0; t < CBS / 4; t += 16) {
        int code = cbase + t + l16;
        const u16* cph = CBh + (size_t)code * CBD + quad * 8;
        const u16* cpl = CBl + (size_t)code * CBD + quad * 8;
        short8 C0h = *(const short8*)cph;
        short8 C1h = *(const short8*)(cph + 32);
        short8 C0l = *(const short8*)cpl;
        short8 C1l = *(const short8*)(cpl + 32);
        float cn = CBN[code];
        f32x4 a = (f32x4){0.f, 0.f, 0.f, 0.f};
        a = __builtin_amdgcn_mfma_f32_16x16x32_bf16(Z0h, C0h, a, 0, 0, 0);
        a = __builtin_amdgcn_mfma_f32_16x16x32_bf16(Z1h, C1h, a, 0, 0, 0);
        a = __builtin_amdgcn_mfma_f32_16x16x32_bf16(Z0l, C0h, a, 0, 0, 0);
        a = __builtin_amdgcn_mfma_f32_16x16x32_bf16(Z1l, C1h, a, 0, 0, 0);
        a = __builtin_amdgcn_mfma_f32_16x16x32_bf16(Z0h, C0l, a, 0, 0, 0);
        a = __builtin_amdgcn_mfma_f32_16x16x32_bf16(Z1h, C1l, a, 0, 0, 0);
#pragma unroll
        for (int r = 0; r < 4; ++r) {
            float s = cn - 2.0f * a[r];
            if (s < best[r]) { best[r] = s; bidx[r] = code; }
        }
    }
#pragma unroll
    for (int off = 8; off; off >>= 1) {
#pragma unroll
        for (int r = 0; r < 4; ++r) {
            float ov = __shfl_xor(best[r], off);
            int oi = __shfl_xor(bidx[r], off);
            if (ov < best[r] || (ov == best[r] && oi < bidx[r])) { best[r] = ov; bidx[r] = oi; }
        }
    }
    if (l16 == 0) {
#pragma unroll
        for (int r = 0; r < 4; ++r) {
            sbest[w][quad * 4 + r] = best[r];
            sidx[w][quad * 4 + r] = bidx[r];
        }
    }
    __syncthreads();
    if (tid < 16) {
        float bv = sbest[0][tid];
        int bi = sidx[0][tid];
#pragma unroll
        for (int ww = 1; ww < 4; ++ww) {
            float ov = sbest[ww][tid];
            int oi = sidx[ww][tid];
            if (ov < bv || (ov == bv && oi < bi)) { bv = ov; bi = oi; }
        }
        ibest[tid] = bi;
    }
    __syncthreads();

    int d2 = lane;
    float qacc = 0.0f, closs = 0.0f;
#pragma unroll
    for (int j = 0; j < 4; ++j) {
        int r2 = w * 4 + j;
        int bi = ibest[r2];
        float q = CB[(size_t)bi * CBD + d2];
        float z = Z[(size_t)(row0 + r2) * CBD + d2];
        qacc += q;
        float df = q - z;
        closs += df * df;
    }
    psum[w][d2] = qacc;
#pragma unroll
    for (int off = 32; off; off >>= 1) closs += __shfl_xor(closs, off);
    if (d2 == 0) cl4[w] = closs;
    __syncthreads();
    if (tid < 64) {
        float t = psum[0][tid] + psum[1][tid] + psum[2][tid] + psum[3][tid];
        int b = row0 >> 9;
        atomicAdd(out + b * 64 + tid, t);
    }
    if (tid == 0)
        atomicAdd(out + 1024, (cl4[0] + cl4[1] + cl4[2] + cl4[3]) * (1.0f / (float)(MROWS * CBD)));
}

// -------------------------------------------------------------------- launch
extern "C" void kernel_launch(void* const* d_in, const int* in_sizes, int n_in,
                              void* d_out, int out_size, void* d_ws, size_t ws_size,
                              hipStream_t stream) {
    const float* x    = (const float*)d_in[0];
    const float* w_in = (const float*)d_in[1];
    const float* b_in = (const float*)d_in[2];
    const float* pos  = (const float*)d_in[3];
    const float* ln1g = (const float*)d_in[4];
    const float* ln1b = (const float*)d_in[5];
    const float* wq   = (const float*)d_in[6];
    const float* wk   = (const float*)d_in[7];
    const float* wv   = (const float*)d_in[8];
    const float* wo   = (const float*)d_in[9];
    const float* ln2g = (const float*)d_in[10];
    const float* ln2b = (const float*)d_in[11];
    const float* ffw1 = (const float*)d_in[12];
    const float* ffb1 = (const float*)d_in[13];
    const float* ffw2 = (const float*)d_in[14];
    const float* ffb2 = (const float*)d_in[15];
    const float* lnfg = (const float*)d_in[16];
    const float* lnfb = (const float*)d_in[17];
    const float* wout = (const float*)d_in[18];
    const float* bout = (const float*)d_in[19];
    const float* cb   = (const float*)d_in[20];
    float* out = (float*)d_out;

    const size_t MD  = (size_t)MROWS * DMODEL;   // 4,194,304
    const size_t MQ  = (size_t)MROWS * 1536;     // 12,582,912
    const size_t MF  = (size_t)MROWS * DFF;      // 16,777,216

    float* ws   = (float*)d_ws;
    float* h    = ws;
    float* t0   = h + MD;
    float* big  = t0 + MD;                   // MF floats (aliased region)
    float* zb   = big + MF;
    float* cbn  = zb + (size_t)MROWS * CBD;
    u16* cbh    = (u16*)(cbn + CBS);
    u16* cbl    = cbh + (size_t)CBS * CBD;
    u16* t0h    = (u16*)(cbh + 2 * (size_t)CBS * CBD);
    u16* t0l    = t0h + MD;
    u16* wb     = t0l + MD;

    // big aliases
    u16* qkvh = (u16*)big;
    u16* qkvl = qkvh + MQ;
    u16* obh  = qkvl + MQ;
    u16* obl  = obh + MD;
    u16* xh   = obh;
    u16* xl   = obl;
    u16* fmh  = (u16*)big;
    u16* fml  = fmh + MF;
    u16* zbh  = (u16*)big;        // VQ phase: big region is dead
    u16* zbl  = zbh + (size_t)MROWS * CBD;

    const size_t S_WIN  = (size_t)DMODEL * DMODEL;
    const size_t S_QKV  = (size_t)1536 * DMODEL * NDEPTH;
    const size_t S_WO   = S_WIN * NDEPTH;
    const size_t S_FF1  = (size_t)DFF * DMODEL * NDEPTH;
    const size_t S_FF2  = S_FF1;
    u16* winT_h = wb;
    u16* winT_l = winT_h + S_WIN;
    u16* qkvT_h = winT_l + S_WIN;
    u16* qkvT_l = qkvT_h + S_QKV;
    u16* woT_h  = qkvT_l + S_QKV;
    u16* woT_l  = woT_h + S_WO;
    u16* ff1T_h = woT_l + S_WO;
    u16* ff1T_l = ff1T_h + S_FF1;
    u16* ff2T_h = ff1T_l + S_FF1;
    u16* ff2T_l = ff2T_h + S_FF2;
    u16* VTh = ff2T_l + S_FF2;
    u16* VTl = VTh + (size_t)BATCH * SEQ * DMODEL;
    // split-K partial buffers (fp32, M x 512 each)
    float* spK0 = (float*)(VTl + (size_t)BATCH * SEQ * DMODEL);
    float* spK1 = spK0 + MD;

    dim3 blk(256);

    zero_kernel<<<dim3((out_size + 255) / 256), blk, 0, stream>>>(out, out_size);
    cbn_kernel<<<dim3(CBS / 256), blk, 0, stream>>>(cb, cbn);
    split_kernel<<<dim3((int)(CBS * CBD / 256)), blk, 0, stream>>>(cb, cbh, cbl, CBS * CBD);

    wtrans_kernel<<<dim3(16, 16, 1), blk, 0, stream>>>(w_in, winT_h, winT_l, DMODEL, DMODEL, 0, 0);
    wtrans_kernel<<<dim3(16, 16, NDEPTH), blk, 0, stream>>>(
        wq, qkvT_h, qkvT_l, DMODEL, DMODEL, (long)DMODEL * DMODEL, (long)1536 * DMODEL);
    wtrans_kernel<<<dim3(16, 16, NDEPTH), blk, 0, stream>>>(
        wk, qkvT_h + (size_t)512 * DMODEL, qkvT_l + (size_t)512 * DMODEL,
        DMODEL, DMODEL, (long)DMODEL * DMODEL, (long)1536 * DMODEL);
    wtrans_kernel<<<dim3(16, 16, NDEPTH), blk, 0, stream>>>(
        wv, qkvT_h + (size_t)1024 * DMODEL, qkvT_l + (size_t)1024 * DMODEL,
        DMODEL, DMODEL, (long)DMODEL * DMODEL, (long)1536 * DMODEL);
    wtrans_kernel<<<dim3(16, 16, NDEPTH), blk, 0, stream>>>(
        wo, woT_h, woT_l, DMODEL, DMODEL, (long)DMODEL * DMODEL, (long)DMODEL * DMODEL);
    wtrans_kernel<<<dim3(DFF / 32, 16, NDEPTH), blk, 0, stream>>>(
        ffw1, ff1T_h, ff1T_l, DMODEL, DFF, (long)DMODEL * DFF, (long)DFF * DMODEL);
    wtrans_kernel<<<dim3(16, DFF / 32, NDEPTH), blk, 0, stream>>>(
        ffw2, ff2T_h, ff2T_l, DFF, DMODEL, (long)DFF * DMODEL, (long)DMODEL * DFF);

    split_kernel<<<dim3((int)(MD / 256)), blk, 0, stream>>>(x, xh, xl, (int)MD);

    // input projection: split-K=2 -> spK0/spK1 (reduced+pos+bias inside ln1 of layer 0)
    gemm3_kernel<<<dim3(MROWS / 128, DMODEL / 128, 2), blk, 0, stream>>>(
        xh, xl, winT_h, winT_l, nullptr, nullptr, nullptr, nullptr, nullptr, nullptr,
        MROWS, DMODEL, DMODEL, 0, spK0, spK1, 256, 0);

    for (int l = 0; l < NDEPTH; ++l) {
        // ln1 folds: l==0 -> input proj (+b_in+pos); l>0 -> previous ff2 (+ffb2[l-1])
        ln_kernel<<<dim3(MROWS / 4), blk, 0, stream>>>(
            (l == 0) ? nullptr : h, spK0, spK1,
            (l == 0) ? b_in : (ffb2 + (size_t)(l - 1) * DMODEL),
            (l == 0) ? pos : nullptr, h,
            nullptr, t0h, t0l, ln1g + l * DMODEL, ln1b + l * DMODEL);
        // fused QKV -> head-major split planes (slot = part*8+head, each [M][64])
        gemm3_kernel<<<dim3(MROWS / 128, 1536 / 128, 1), blk, 0, stream>>>(
            t0h, t0l, qkvT_h + (size_t)l * 1536 * DMODEL, qkvT_l + (size_t)l * 1536 * DMODEL,
            nullptr, qkvh, qkvl, nullptr, nullptr, nullptr, MROWS, 1536, DMODEL, 0,
            nullptr, nullptr, 0, 1);
        vtrans_kernel<<<dim3(8, 8, 32), blk, 0, stream>>>(qkvh, qkvl, VTh, VTl);
        attn_flash_kernel<<<dim3(1024), blk, 0, stream>>>(
            qkvh, qkvl, VTh, VTl, obh, obl);
        // wo: split-K=2 (reduced + residual inside ln2)
        gemm3_kernel<<<dim3(MROWS / 128, DMODEL / 128, 2), blk, 0, stream>>>(
            obh, obl, woT_h + (size_t)l * S_WIN, woT_l + (size_t)l * S_WIN,
            nullptr, nullptr, nullptr, nullptr, nullptr, nullptr,
            MROWS, DMODEL, DMODEL, 0, spK0, spK1, 256, 0);
        ln_kernel<<<dim3(MROWS / 4), blk, 0, stream>>>(
            h, spK0, spK1, nullptr, nullptr, h,
            nullptr, t0h, t0l, ln2g + l * DMODEL, ln2b + l * DMODEL);
        gemm3_kernel<<<dim3(MROWS / 128, DFF / 128, 1), blk, 0, stream>>>(
            t0h, t0l, ff1T_h + (size_t)l * DFF * DMODEL, ff1T_l + (size_t)l * DFF * DMODEL,
            nullptr, fmh, fml, ffb1 + l * DFF, nullptr, nullptr, MROWS, DFF, DMODEL, 1,
            nullptr, nullptr, 0, 0);
        // ff2: split-K=2 over K=2048 (reduced + ffb2 + residual in next ln1/lnf)
        gemm3_kernel<<<dim3(MROWS / 128, DMODEL / 128, 2), blk, 0, stream>>>(
            fmh, fml, ff2T_h + (size_t)l * DFF * DMODEL, ff2T_l + (size_t)l * DFF * DMODEL,
            nullptr, nullptr, nullptr, nullptr, nullptr, nullptr,
            MROWS, DMODEL, DFF, 0, spK0, spK1, 1024, 0);
    }

    // final ln folds last ff2 (+ffb2[3]); writes fp32 t0 for the out-projection
    ln_kernel<<<dim3(MROWS / 4), blk, 0, stream>>>(
        h, spK0, spK1, ffb2 + (size_t)3 * DMODEL, nullptr, nullptr,
        t0, nullptr, nullptr, lnfg, lnfb);
    gemm_kernel<<<dim3(MROWS / 64, 1), blk, 0, stream>>>(t0, wout, zb, bout, MROWS, CBD, DMODEL);
    split_kernel<<<dim3((int)((size_t)MROWS * CBD / 256)), blk, 0, stream>>>(
        zb, zbh, zbl, MROWS * CBD);
    vq3_kernel<<<dim3(MROWS / 16), blk, 0, stream>>>(zb, zbh, zbl, cbh, cbl, cb, cbn, out);
}

// Round 9
// 1815.730 us; speedup vs baseline: 1.0693x; 1.0549x over previous
//
#include <hip/hip_runtime.h>
#include <cmath>

#define BATCH 16
#define SEQ 512
#define DMODEL 512
#define NDEPTH 4
#define NHEADS 8
#define DHEAD 64
#define DFF 2048
#define CBD 64
#define CBS 8192
#define MROWS (BATCH * SEQ) // 8192

typedef unsigned short u16;
typedef __attribute__((ext_vector_type(8))) short short8; // 8 bf16 = 4 VGPRs (MFMA A/B frag)
typedef __attribute__((ext_vector_type(4))) float f32x4;  // MFMA C/D frag
typedef __attribute__((ext_vector_type(4))) unsigned short u16x4;

// ---------------------------------------------------------------- bf16 helpers
__device__ __forceinline__ u16 f2bf(float f) {
    unsigned u = __float_as_uint(f);
    u += 0x7fff + ((u >> 16) & 1); // RNE
    return (u16)(u >> 16);
}
__device__ __forceinline__ float bf2f(u16 h) {
    return __uint_as_float(((unsigned)h) << 16);
}

// async global->LDS 16B: LDS dest must be wave-uniform base + lane*16
__device__ __forceinline__ void async16(u16* lds, const u16* g) {
    __builtin_amdgcn_global_load_lds(
        (const __attribute__((address_space(1))) unsigned int*)g,
        (__attribute__((address_space(3))) unsigned int*)lds, 16, 0, 0);
}

// gelu(u) = 0.5u(1+tanh(y)) = u*sigmoid(2y) — exp-form, __expf -> v_exp_f32
__device__ __forceinline__ float gelu_tanh(float u) {
    float t = fmaf(0.07135481627f * u, u * u, 1.5957691216f * u);
    return u / (1.0f + __expf(-t));
}

// ---------------------------------------------------------------- zero output
__global__ void zero_kernel(float* __restrict__ p, int n) {
    int i = blockIdx.x * 256 + threadIdx.x;
    if (i < n) p[i] = 0.0f;
}

// ------------------------------------------------------------- codebook norms
__global__ void cbn_kernel(const float* __restrict__ cb, float* __restrict__ cbn) {
    int c = blockIdx.x * 256 + threadIdx.x;
    if (c >= CBS) return;
    const float* row = cb + (size_t)c * CBD;
    float s = 0.0f;
#pragma unroll
    for (int d = 0; d < CBD; ++d) s += row[d] * row[d];
    cbn[c] = s;
}

// ------------------------- weight transpose + split: W [z][K][N] -> T [z][N][K]
__global__ __launch_bounds__(256) void wtrans_kernel(
    const float* __restrict__ W, u16* __restrict__ Th, u16* __restrict__ Tl,
    int K, int N, long inLS, long outLS) {
    __shared__ float t[32][33];
    const float* Ws = W + (size_t)blockIdx.z * inLS;
    u16* Tho = Th + (size_t)blockIdx.z * outLS;
    u16* Tlo = Tl + (size_t)blockIdx.z * outLS;
    int n0 = blockIdx.x * 32, k0 = blockIdx.y * 32;
    int tx = threadIdx.x & 31, ty = threadIdx.x >> 5;
#pragma unroll
    for (int r = ty; r < 32; r += 8) t[r][tx] = Ws[(size_t)(k0 + r) * N + n0 + tx];
    __syncthreads();
#pragma unroll
    for (int r = ty; r < 32; r += 8) {
        float v = t[tx][r];
        size_t o = (size_t)(n0 + r) * K + k0 + tx;
        u16 hh = f2bf(v);
        Tho[o] = hh;
        Tlo[o] = f2bf(v - bf2f(hh));
    }
}

// ---------------- V transpose: head-major qkv slot [16+h][M][64] -> VT [b][d][s]
__global__ __launch_bounds__(256) void vtrans_kernel(
    const u16* __restrict__ Qh, const u16* __restrict__ Ql,
    u16* __restrict__ VTh, u16* __restrict__ VTl) {
    __shared__ u16 t[64][68];
    int s0 = blockIdx.x * 64;       // seq tile
    int hh = blockIdx.y;            // head
    int b = blockIdx.z & 15, plane = blockIdx.z >> 4;
    const u16* src = (plane ? Ql : Qh) + ((size_t)(16 + hh) * MROWS) * 64;
    u16* dst = (plane ? VTl : VTh);
    int tid = threadIdx.x;
    int rr = tid >> 4, c4 = (tid & 15) * 4;
#pragma unroll
    for (int i = 0; i < 4; ++i) {
        int r = rr + i * 16; // seq within tile
        const u16* p = src + (size_t)(b * SEQ + s0 + r) * 64 + c4;
        *(u16x4*)(&t[r][c4]) = *(const u16x4*)p;
    }
    __syncthreads();
#pragma unroll
    for (int i = 0; i < 4; ++i) {
        int r = rr + i * 16; // d-index within head
        u16x4 v;
        v.x = t[c4 + 0][r]; v.y = t[c4 + 1][r]; v.z = t[c4 + 2][r]; v.w = t[c4 + 3][r];
        *(u16x4*)(dst + (size_t)b * SEQ * DMODEL + (size_t)(hh * 64 + r) * SEQ + s0 + c4) = v;
    }
}

// ------------------------------------------------ elementwise fp32 -> (hi,lo)
__global__ void split_kernel(const float* __restrict__ X, u16* __restrict__ H,
                             u16* __restrict__ L, int n) {
    int i = blockIdx.x * 256 + threadIdx.x;
    if (i < n) {
        float v = X[i];
        u16 hh = f2bf(v);
        H[i] = hh;
        L[i] = f2bf(v - bf2f(hh));
    }
}

// ---------------------------------------- layernorm (+split-K reduce folding)
__global__ __launch_bounds__(256) void ln_kernel(
    const float* __restrict__ X,
    const float* __restrict__ C0, const float* __restrict__ C1,
    const float* __restrict__ bias2, const float* __restrict__ pos2,
    float* __restrict__ Xout,
    float* __restrict__ Y, u16* __restrict__ Yh, u16* __restrict__ Yl,
    const float* __restrict__ g, const float* __restrict__ b) {
    int row  = blockIdx.x * 4 + (threadIdx.x >> 6);
    int lane = threadIdx.x & 63;
    float v[8];
    float s = 0.0f;
#pragma unroll
    for (int j = 0; j < 8; ++j) {
        int d = lane + j * 64;
        size_t o = (size_t)row * DMODEL + d;
        float t = X ? X[o] : 0.0f;
        if (C0)    t += C0[o] + C1[o];
        if (bias2) t += bias2[d];
        if (pos2)  t += pos2[(size_t)(row & (SEQ - 1)) * DMODEL + d];
        v[j] = t;
        if (Xout) Xout[o] = t;
        s += t;
    }
#pragma unroll
    for (int off = 32; off; off >>= 1) s += __shfl_xor(s, off);
    float mu  = s * (1.0f / DMODEL);
    float var = 0.0f;
#pragma unroll
    for (int j = 0; j < 8; ++j) { float d = v[j] - mu; var += d * d; }
#pragma unroll
    for (int off = 32; off; off >>= 1) var += __shfl_xor(var, off);
    float r = rsqrtf(var * (1.0f / DMODEL) + 1e-5f);
#pragma unroll
    for (int j = 0; j < 8; ++j) {
        int d = lane + j * 64;
        float y = (v[j] - mu) * r * g[d] + b[d];
        size_t o = (size_t)row * DMODEL + d;
        if (Y) Y[o] = y;
        if (Yh) {
            u16 hh = f2bf(y);
            Yh[o] = hh;
            Yl[o] = f2bf(y - bf2f(hh));
        }
    }
}

// --------------------------------------------------------- bf16x3 MFMA GEMM
// BK=64, XOR-swizzled LDS (conflict-free frag reads), 96 MFMA per barrier-pair.
// LDS chunk (row, c) holds global chunk c ^ (row&7); global_load_lds's global
// address is per-lane so the permutation lives on the fetch side (coalesced:
// permutes within each 128B row). kslice>0: split-K partials -> Cs0/Cs1.
// qkvscatter: store C head-major — o = ((n>>6)*M + m)*64 + (n&63).
__global__ __launch_bounds__(256) void gemm3_kernel(
    const u16* __restrict__ Ah, const u16* __restrict__ Al,
    const u16* __restrict__ Bh, const u16* __restrict__ Bl,
    float* __restrict__ Cf, u16* __restrict__ Ch, u16* __restrict__ Cl,
    const float* __restrict__ bias, const float* __restrict__ res,
    const float* __restrict__ pos, int M, int N, int K, int gelu,
    float* __restrict__ Cs0, float* __restrict__ Cs1, int kslice, int qkvscatter) {
    __shared__ __align__(16) u16 AsH[128 * 64];
    __shared__ __align__(16) u16 AsL[128 * 64];
    __shared__ __align__(16) u16 BsH[128 * 64];
    __shared__ __align__(16) u16 BsL[128 * 64];

    int tid  = threadIdx.x;
    int w    = tid >> 6, lane = tid & 63;
    int wr   = w >> 1, wc = w & 1;
    int quad = lane >> 4, l16 = lane & 15;
    int m0   = blockIdx.x * 128;
    int n0   = blockIdx.y * 128;
    int ksA  = (kslice > 0) ? blockIdx.z * kslice : 0;
    int ksB  = (kslice > 0) ? ksA + kslice : K;

    f32x4 acc[4][4];
#pragma unroll
    for (int i = 0; i < 4; ++i)
#pragma unroll
        for (int j = 0; j < 4; ++j) acc[i][j] = (f32x4){0.f, 0.f, 0.f, 0.f};

    // staging map: chunk cidx = tid + 256*r (r=0..3); row=cidx>>3, cslot=cidx&7;
    // fetch global chunk cg = cslot ^ (row&7); LDS elem offset = cidx*8
    int ldsoff[4];
    size_t goff[4];
#pragma unroll
    for (int r = 0; r < 4; ++r) {
        int cidx = tid + 256 * r;
        int row = cidx >> 3;
        int cg = (cidx & 7) ^ (row & 7);
        ldsoff[r] = cidx * 8;
        goff[r] = (size_t)row * K + cg * 8;
    }

    const u16* AbaseH = Ah + (size_t)m0 * K;
    const u16* AbaseL = Al + (size_t)m0 * K;
    const u16* BbaseH = Bh + (size_t)n0 * K;
    const u16* BbaseL = Bl + (size_t)n0 * K;

    for (int ks = ksA; ks < ksB; ks += 64) {
        __syncthreads();
#pragma unroll
        for (int r = 0; r < 4; ++r) {
            size_t g = goff[r] + ks;
            async16(&AsH[ldsoff[r]], AbaseH + g);
            async16(&AsL[ldsoff[r]], AbaseL + g);
            async16(&BsH[ldsoff[r]], BbaseH + g);
            async16(&BsL[ldsoff[r]], BbaseL + g);
        }
        __syncthreads();
#pragma unroll
        for (int s = 0; s < 2; ++s) {
            short8 afh[4], afl[4];
#pragma unroll
            for (int i = 0; i < 4; ++i) {
                int row = wr * 64 + i * 16 + l16;
                int off = row * 64 + (((s << 2) | quad) ^ (row & 7)) * 8;
                afh[i] = *(const short8*)&AsH[off];
                afl[i] = *(const short8*)&AsL[off];
            }
#pragma unroll
            for (int j = 0; j < 4; ++j) {
                int rowb = wc * 64 + j * 16 + l16;
                int offb = rowb * 64 + (((s << 2) | quad) ^ (rowb & 7)) * 8;
                short8 bh = *(const short8*)&BsH[offb];
                short8 bl = *(const short8*)&BsL[offb];
#pragma unroll
                for (int i = 0; i < 4; ++i) {
                    acc[i][j] = __builtin_amdgcn_mfma_f32_16x16x32_bf16(afh[i], bh, acc[i][j], 0, 0, 0);
                    acc[i][j] = __builtin_amdgcn_mfma_f32_16x16x32_bf16(afl[i], bh, acc[i][j], 0, 0, 0);
                    acc[i][j] = __builtin_amdgcn_mfma_f32_16x16x32_bf16(afh[i], bl, acc[i][j], 0, 0, 0);
                }
            }
        }
    }

    float* Cspl = (kslice > 0) ? (blockIdx.z ? Cs1 : Cs0) : nullptr;
    int mbase = m0 + wr * 64;
    int nbase = n0 + wc * 64;
#pragma unroll
    for (int mi = 0; mi < 4; ++mi)
#pragma unroll
        for (int ni = 0; ni < 4; ++ni) {
            f32x4 a = acc[mi][ni];
#pragma unroll
            for (int r = 0; r < 4; ++r) {
                int m = mbase + mi * 16 + quad * 4 + r;
                int n = nbase + ni * 16 + l16;
                float v = a[r];
                size_t o = qkvscatter
                    ? ((size_t)(n >> 6) * M + m) * 64 + (n & 63)
                    : (size_t)m * N + n;
                if (Cspl) { Cspl[o] = v; continue; }
                if (bias) v += bias[n];
                if (pos)  v += pos[(size_t)(m & (SEQ - 1)) * N + n];
                if (res)  v += res[(size_t)m * N + n];
                if (gelu) v = gelu_tanh(v);
                if (Cf) Cf[o] = v;
                if (Ch) {
                    u16 hh = f2bf(v);
                    Ch[o] = hh;
                    Cl[o] = f2bf(v - bf2f(hh));
                }
            }
        }
}

// ------------------------------------------------------------ fp32 GEMM (small)
__global__ __launch_bounds__(256) void gemm_kernel(
    const float* __restrict__ A, const float* __restrict__ Bm,
    float* __restrict__ C, const float* __restrict__ bias,
    int M, int N, int K) {
    __shared__ float As[16][68];
    __shared__ float Bs[16][64];
    int tid = threadIdx.x;
    int tx = tid & 15, ty = tid >> 4;
    int a_m = tid >> 2, a_k = (tid & 3) * 4;
    int b_k = tid >> 4, b_n = (tid & 15) * 4;
    const float* Arow = A + (size_t)(blockIdx.x * 64 + a_m) * K;
    const float* Bcol = Bm + (size_t)blockIdx.y * 64 + b_n;
    float acc[4][4] = {};
    for (int k0 = 0; k0 < K; k0 += 16) {
        float4 av = *(const float4*)(Arow + k0 + a_k);
        float4 bv = *(const float4*)(Bcol + (size_t)(k0 + b_k) * N);
        __syncthreads();
        As[a_k + 0][a_m] = av.x; As[a_k + 1][a_m] = av.y;
        As[a_k + 2][a_m] = av.z; As[a_k + 3][a_m] = av.w;
        *(float4*)(&Bs[b_k][b_n]) = bv;
        __syncthreads();
#pragma unroll
        for (int kk = 0; kk < 16; ++kk) {
            float4 a4 = *(const float4*)(&As[kk][ty * 4]);
            float4 b4 = *(const float4*)(&Bs[kk][tx * 4]);
            float ar[4] = {a4.x, a4.y, a4.z, a4.w};
            float br[4] = {b4.x, b4.y, b4.z, b4.w};
#pragma unroll
            for (int i = 0; i < 4; ++i)
#pragma unroll
                for (int j = 0; j < 4; ++j) acc[i][j] = fmaf(ar[i], br[j], acc[i][j]);
        }
    }
    int m0 = blockIdx.x * 64 + ty * 4;
    int n0 = blockIdx.y * 64 + tx * 4;
#pragma unroll
    for (int i = 0; i < 4; ++i) {
        float vv[4];
#pragma unroll
        for (int j = 0; j < 4; ++j) {
            float t = acc[i][j];
            if (bias) t += bias[n0 + j];
            vv[j] = t;
        }
        *(float4*)(C + (size_t)(m0 + i) * N + n0) = make_float4(vv[0], vv[1], vv[2], vv[3]);
    }
}

// ------------------------------------------- flash attention (online softmax)
__global__ __launch_bounds__(256) void attn_flash_kernel(
    const u16* __restrict__ QKh, const u16* __restrict__ QKl,
    const u16* __restrict__ VTh, const u16* __restrict__ VTl,
    u16* __restrict__ Oh, u16* __restrict__ Ol) {
    int bh = blockIdx.x & 127;
    int qt = blockIdx.x >> 7;   // 0..7
    int bb = bh >> 3, hh = bh & 7;

    __shared__ __align__(16) float Pw[4][16 * 68]; // wave-private P tiles (17408 B)

    int tid = threadIdx.x;
    int w = tid >> 6, lane = tid & 63;
    int quad = lane >> 4, l16 = lane & 15;
    int qtile = qt * 4 + w;     // 0..31
    float* P = Pw[w];

    const u16* qrh = QKh + ((size_t)hh * MROWS + bb * SEQ + qtile * 16 + l16) * 64 + quad * 8;
    const u16* qrl = QKl + ((size_t)hh * MROWS + bb * SEQ + qtile * 16 + l16) * 64 + quad * 8;
    short8 Qh0 = *(const short8*)qrh;
    short8 Qh1 = *(const short8*)(qrh + 32);
    short8 Ql0 = *(const short8*)qrl;
    short8 Ql1 = *(const short8*)(qrl + 32);

    float m[4] = {-1e30f, -1e30f, -1e30f, -1e30f};
    float lsum[4] = {0.f, 0.f, 0.f, 0.f};
    f32x4 acc[4];
#pragma unroll
    for (int dt = 0; dt < 4; ++dt) acc[dt] = (f32x4){0.f, 0.f, 0.f, 0.f};

    const u16* KbH = QKh + ((size_t)(8 + hh) * MROWS + bb * SEQ) * 64;
    const u16* KbL = QKl + ((size_t)(8 + hh) * MROWS + bb * SEQ) * 64;
    const u16* VbH = VTh + (size_t)bb * SEQ * DMODEL + (size_t)(hh * 64) * SEQ;
    const u16* VbL = VTl + (size_t)bb * SEQ * DMODEL + (size_t)(hh * 64) * SEQ;

    for (int kt = 0; kt < 8; ++kt) {
        int kb = kt * 64;
        f32x4 st[4];
#pragma unroll
        for (int s = 0; s < 4; ++s) {
            const u16* kh = KbH + (size_t)(kb + s * 16 + l16) * 64 + quad * 8;
            const u16* kl = KbL + (size_t)(kb + s * 16 + l16) * 64 + quad * 8;
            short8 Kh0 = *(const short8*)kh;
            short8 Kh1 = *(const short8*)(kh + 32);
            short8 Kl0 = *(const short8*)kl;
            short8 Kl1 = *(const short8*)(kl + 32);
            f32x4 a = (f32x4){0.f, 0.f, 0.f, 0.f};
            a = __builtin_amdgcn_mfma_f32_16x16x32_bf16(Qh0, Kh0, a, 0, 0, 0);
            a = __builtin_amdgcn_mfma_f32_16x16x32_bf16(Qh1, Kh1, a, 0, 0, 0);
            a = __builtin_amdgcn_mfma_f32_16x16x32_bf16(Ql0, Kh0, a, 0, 0, 0);
            a = __builtin_amdgcn_mfma_f32_16x16x32_bf16(Ql1, Kh1, a, 0, 0, 0);
            a = __builtin_amdgcn_mfma_f32_16x16x32_bf16(Qh0, Kl0, a, 0, 0, 0);
            a = __builtin_amdgcn_mfma_f32_16x16x32_bf16(Qh1, Kl1, a, 0, 0, 0);
            st[s] = a * 0.125f;
        }
        float alpha[4];
#pragma unroll
        for (int r = 0; r < 4; ++r) {
            float mx = fmaxf(fmaxf(st[0][r], st[1][r]), fmaxf(st[2][r], st[3][r]));
#pragma unroll
            for (int off = 8; off; off >>= 1) mx = fmaxf(mx, __shfl_xor(mx, off));
            float mn = fmaxf(m[r], mx);
            alpha[r] = __expf(m[r] - mn);
            m[r] = mn;
        }
#pragma unroll
        for (int r = 0; r < 4; ++r) {
            float rs = 0.f;
#pragma unroll
            for (int s = 0; s < 4; ++s) {
                float p = __expf(st[s][r] - m[r]);
                st[s][r] = p;
                rs += p;
            }
#pragma unroll
            for (int off = 8; off; off >>= 1) rs += __shfl_xor(rs, off);
            lsum[r] = lsum[r] * alpha[r] + rs;
        }
#pragma unroll
        for (int dt = 0; dt < 4; ++dt)
#pragma unroll
            for (int r = 0; r < 4; ++r) acc[dt][r] *= alpha[r];
#pragma unroll
        for (int s = 0; s < 4; ++s)
#pragma unroll
            for (int r = 0; r < 4; ++r)
                P[(quad * 4 + r) * 68 + s * 16 + l16] = st[s][r];
        short8 ph[2], pl[2];
#pragma unroll
        for (int ks = 0; ks < 2; ++ks) {
            const float* src = &P[l16 * 68 + ks * 32 + quad * 8];
            f32x4 a0 = *(const f32x4*)src;
            f32x4 a1 = *(const f32x4*)(src + 4);
            float v[8] = {a0[0], a0[1], a0[2], a0[3], a1[0], a1[1], a1[2], a1[3]};
#pragma unroll
            for (int j = 0; j < 8; ++j) {
                u16 hv = f2bf(v[j]);
                ph[ks][j] = (short)hv;
                pl[ks][j] = (short)f2bf(v[j] - bf2f(hv));
            }
        }
#pragma unroll
        for (int dt = 0; dt < 4; ++dt) {
            const u16* vh = VbH + (size_t)(dt * 16 + l16) * SEQ + kb + quad * 8;
            const u16* vl = VbL + (size_t)(dt * 16 + l16) * SEQ + kb + quad * 8;
            short8 Vh0 = *(const short8*)vh;
            short8 Vh1 = *(const short8*)(vh + 32);
            short8 Vl0 = *(const short8*)vl;
            short8 Vl1 = *(const short8*)(vl + 32);
            acc[dt] = __builtin_amdgcn_mfma_f32_16x16x32_bf16(ph[0], Vh0, acc[dt], 0, 0, 0);
            acc[dt] = __builtin_amdgcn_mfma_f32_16x16x32_bf16(ph[1], Vh1, acc[dt], 0, 0, 0);
            acc[dt] = __builtin_amdgcn_mfma_f32_16x16x32_bf16(pl[0], Vh0, acc[dt], 0, 0, 0);
            acc[dt] = __builtin_amdgcn_mfma_f32_16x16x32_bf16(pl[1], Vh1, acc[dt], 0, 0, 0);
            acc[dt] = __builtin_amdgcn_mfma_f32_16x16x32_bf16(ph[0], Vl0, acc[dt], 0, 0, 0);
            acc[dt] = __builtin_amdgcn_mfma_f32_16x16x32_bf16(ph[1], Vl1, acc[dt], 0, 0, 0);
        }
    }

#pragma unroll
    for (int r = 0; r < 4; ++r) {
        float inv = 1.0f / lsum[r];
        size_t rowoff = (size_t)(bb * SEQ + qtile * 16 + quad * 4 + r) * DMODEL + hh * 64;
#pragma unroll
        for (int dt = 0; dt < 4; ++dt) {
            float v = acc[dt][r] * inv;
            u16 hv = f2bf(v);
            Oh[rowoff + dt * 16 + l16] = hv;
            Ol[rowoff + dt * 16 + l16] = f2bf(v - bf2f(hv));
        }
    }
}

// ----------------------------------------------------------------- MFMA VQ
__global__ __launch_bounds__(256) void vq3_kernel(
    const float* __restrict__ Z, const u16* __restrict__ Zh, const u16* __restrict__ Zl,
    const u16* __restrict__ CBh, const u16* __restrict__ CBl,
    const float* __restrict__ CB, const float* __restrict__ CBN,
    float* __restrict__ out) {
    __shared__ float sbest[4][16];
    __shared__ int sidx[4][16];
    __shared__ int ibest[16];
    __shared__ float psum[4][64];
    __shared__ float cl4[4];

    int tid = threadIdx.x;
    int w = tid >> 6, lane = tid & 63;
    int quad = lane >> 4, l16 = lane & 15;
    int row0 = blockIdx.x * 16;

    const u16* zph = Zh + (size_t)(row0 + l16) * CBD + quad * 8;
    const u16* zpl = Zl + (size_t)(row0 + l16) * CBD + quad * 8;
    short8 Z0h = *(const short8*)zph;
    short8 Z1h = *(const short8*)(zph + 32);
    short8 Z0l = *(const short8*)zpl;
    short8 Z1l = *(const short8*)(zpl + 32);

    float best[4] = {3.4e38f, 3.4e38f, 3.4e38f, 3.4e38f};
    int bidx[4] = {0, 0, 0, 0};

    int cbase = w * (CBS / 4);
#pragma unroll 2
    for (int t = 0; t < CBS / 4; t += 16) {
        int code = cbase + t + l16;
        const u16* cph = CBh + (size_t)code * CBD + quad * 8;
        const u16* cpl = CBl + (size_t)code * CBD + quad * 8;
        short8 C0h = *(const short8*)cph;
        short8 C1h = *(const short8*)(cph + 32);
        short8 C0l = *(const short8*)cpl;
        short8 C1l = *(const short8*)(cpl + 32);
        float cn = CBN[code];
        f32x4 a = (f32x4){0.f, 0.f, 0.f, 0.f};
        a = __builtin_amdgcn_mfma_f32_16x16x32_bf16(Z0h, C0h, a, 0, 0, 0);
        a = __builtin_amdgcn_mfma_f32_16x16x32_bf16(Z1h, C1h, a, 0, 0, 0);
        a = __builtin_amdgcn_mfma_f32_16x16x32_bf16(Z0l, C0h, a, 0, 0, 0);
        a = __builtin_amdgcn_mfma_f32_16x16x32_bf16(Z1l, C1h, a, 0, 0, 0);
        a = __builtin_amdgcn_mfma_f32_16x16x32_bf16(Z0h, C0l, a, 0, 0, 0);
        a = __builtin_amdgcn_mfma_f32_16x16x32_bf16(Z1h, C1l, a, 0, 0, 0);
#pragma unroll
        for (int r = 0; r < 4; ++r) {
            float s = cn - 2.0f * a[r];
            if (s < best[r]) { best[r] = s; bidx[r] = code; }
        }
    }
#pragma unroll
    for (int off = 8; off; off >>= 1) {
#pragma unroll
        for (int r = 0; r < 4; ++r) {
            float ov = __shfl_xor(best[r], off);
            int oi = __shfl_xor(bidx[r], off);
            if (ov < best[r] || (ov == best[r] && oi < bidx[r])) { best[r] = ov; bidx[r] = oi; }
        }
    }
    if (l16 == 0) {
#pragma unroll
        for (int r = 0; r < 4; ++r) {
            sbest[w][quad * 4 + r] = best[r];
            sidx[w][quad * 4 + r] = bidx[r];
        }
    }
    __syncthreads();
    if (tid < 16) {
        float bv = sbest[0][tid];
        int bi = sidx[0][tid];
#pragma unroll
        for (int ww = 1; ww < 4; ++ww) {
            float ov = sbest[ww][tid];
            int oi = sidx[ww][tid];
            if (ov < bv || (ov == bv && oi < bi)) { bv = ov; bi = oi; }
        }
        ibest[tid] = bi;
    }
    __syncthreads();

    int d2 = lane;
    float qacc = 0.0f, closs = 0.0f;
#pragma unroll
    for (int j = 0; j < 4; ++j) {
        int r2 = w * 4 + j;
        int bi = ibest[r2];
        float q = CB[(size_t)bi * CBD + d2];
        float z = Z[(size_t)(row0 + r2) * CBD + d2];
        qacc += q;
        float df = q - z;
        closs += df * df;
    }
    psum[w][d2] = qacc;
#pragma unroll
    for (int off = 32; off; off >>= 1) closs += __shfl_xor(closs, off);
    if (d2 == 0) cl4[w] = closs;
    __syncthreads();
    if (tid < 64) {
        float t = psum[0][tid] + psum[1][tid] + psum[2][tid] + psum[3][tid];
        int b = row0 >> 9;
        atomicAdd(out + b * 64 + tid, t);
    }
    if (tid == 0)
        atomicAdd(out + 1024, (cl4[0] + cl4[1] + cl4[2] + cl4[3]) * (1.0f / (float)(MROWS * CBD)));
}

// -------------------------------------------------------------------- launch
extern "C" void kernel_launch(void* const* d_in, const int* in_sizes, int n_in,
                              void* d_out, int out_size, void* d_ws, size_t ws_size,
                              hipStream_t stream) {
    const float* x    = (const float*)d_in[0];
    const float* w_in = (const float*)d_in[1];
    const float* b_in = (const float*)d_in[2];
    const float* pos  = (const float*)d_in[3];
    const float* ln1g = (const float*)d_in[4];
    const float* ln1b = (const float*)d_in[5];
    const float* wq   = (const float*)d_in[6];
    const float* wk   = (const float*)d_in[7];
    const float* wv   = (const float*)d_in[8];
    const float* wo   = (const float*)d_in[9];
    const float* ln2g = (const float*)d_in[10];
    const float* ln2b = (const float*)d_in[11];
    const float* ffw1 = (const float*)d_in[12];
    const float* ffb1 = (const float*)d_in[13];
    const float* ffw2 = (const float*)d_in[14];
    const float* ffb2 = (const float*)d_in[15];
    const float* lnfg = (const float*)d_in[16];
    const float* lnfb = (const float*)d_in[17];
    const float* wout = (const float*)d_in[18];
    const float* bout = (const float*)d_in[19];
    const float* cb   = (const float*)d_in[20];
    float* out = (float*)d_out;

    const size_t MD  = (size_t)MROWS * DMODEL;   // 4,194,304
    const size_t MQ  = (size_t)MROWS * 1536;     // 12,582,912
    const size_t MF  = (size_t)MROWS * DFF;      // 16,777,216

    float* ws   = (float*)d_ws;
    float* h    = ws;
    float* t0   = h + MD;
    float* big  = t0 + MD;                   // MF floats (aliased region)
    float* zb   = big + MF;
    float* cbn  = zb + (size_t)MROWS * CBD;
    u16* cbh    = (u16*)(cbn + CBS);
    u16* cbl    = cbh + (size_t)CBS * CBD;
    u16* t0h    = (u16*)(cbh + 2 * (size_t)CBS * CBD);
    u16* t0l    = t0h + MD;
    u16* wb     = t0l + MD;

    // big aliases
    u16* qkvh = (u16*)big;
    u16* qkvl = qkvh + MQ;
    u16* obh  = qkvl + MQ;
    u16* obl  = obh + MD;
    u16* xh   = obh;
    u16* xl   = obl;
    u16* fmh  = (u16*)big;
    u16* fml  = fmh + MF;
    u16* zbh  = (u16*)big;        // VQ phase: big region is dead
    u16* zbl  = zbh + (size_t)MROWS * CBD;

    const size_t S_WIN  = (size_t)DMODEL * DMODEL;
    const size_t S_QKV  = (size_t)1536 * DMODEL * NDEPTH;
    const size_t S_WO   = S_WIN * NDEPTH;
    const size_t S_FF1  = (size_t)DFF * DMODEL * NDEPTH;
    const size_t S_FF2  = S_FF1;
    u16* winT_h = wb;
    u16* winT_l = winT_h + S_WIN;
    u16* qkvT_h = winT_l + S_WIN;
    u16* qkvT_l = qkvT_h + S_QKV;
    u16* woT_h  = qkvT_l + S_QKV;
    u16* woT_l  = woT_h + S_WO;
    u16* ff1T_h = woT_l + S_WO;
    u16* ff1T_l = ff1T_h + S_FF1;
    u16* ff2T_h = ff1T_l + S_FF1;
    u16* ff2T_l = ff2T_h + S_FF2;
    u16* VTh = ff2T_l + S_FF2;
    u16* VTl = VTh + (size_t)BATCH * SEQ * DMODEL;
    // split-K partial buffers (fp32, M x 512 each)
    float* spK0 = (float*)(VTl + (size_t)BATCH * SEQ * DMODEL);
    float* spK1 = spK0 + MD;

    dim3 blk(256);

    zero_kernel<<<dim3((out_size + 255) / 256), blk, 0, stream>>>(out, out_size);
    cbn_kernel<<<dim3(CBS / 256), blk, 0, stream>>>(cb, cbn);
    split_kernel<<<dim3((int)(CBS * CBD / 256)), blk, 0, stream>>>(cb, cbh, cbl, CBS * CBD);

    wtrans_kernel<<<dim3(16, 16, 1), blk, 0, stream>>>(w_in, winT_h, winT_l, DMODEL, DMODEL, 0, 0);
    wtrans_kernel<<<dim3(16, 16, NDEPTH), blk, 0, stream>>>(
        wq, qkvT_h, qkvT_l, DMODEL, DMODEL, (long)DMODEL * DMODEL, (long)1536 * DMODEL);
    wtrans_kernel<<<dim3(16, 16, NDEPTH), blk, 0, stream>>>(
        wk, qkvT_h + (size_t)512 * DMODEL, qkvT_l + (size_t)512 * DMODEL,
        DMODEL, DMODEL, (long)DMODEL * DMODEL, (long)1536 * DMODEL);
    wtrans_kernel<<<dim3(16, 16, NDEPTH), blk, 0, stream>>>(
        wv, qkvT_h + (size_t)1024 * DMODEL, qkvT_l + (size_t)1024 * DMODEL,
        DMODEL, DMODEL, (long)DMODEL * DMODEL, (long)1536 * DMODEL);
    wtrans_kernel<<<dim3(16, 16, NDEPTH), blk, 0, stream>>>(
        wo, woT_h, woT_l, DMODEL, DMODEL, (long)DMODEL * DMODEL, (long)DMODEL * DMODEL);
    wtrans_kernel<<<dim3(DFF / 32, 16, NDEPTH), blk, 0, stream>>>(
        ffw1, ff1T_h, ff1T_l, DMODEL, DFF, (long)DMODEL * DFF, (long)DFF * DMODEL);
    wtrans_kernel<<<dim3(16, DFF / 32, NDEPTH), blk, 0, stream>>>(
        ffw2, ff2T_h, ff2T_l, DFF, DMODEL, (long)DFF * DMODEL, (long)DMODEL * DFF);

    split_kernel<<<dim3((int)(MD / 256)), blk, 0, stream>>>(x, xh, xl, (int)MD);

    // input projection: split-K=2 -> spK0/spK1 (reduced+pos+bias inside ln1 of layer 0)
    gemm3_kernel<<<dim3(MROWS / 128, DMODEL / 128, 2), blk, 0, stream>>>(
        xh, xl, winT_h, winT_l, nullptr, nullptr, nullptr, nullptr, nullptr, nullptr,
        MROWS, DMODEL, DMODEL, 0, spK0, spK1, 256, 0);

    for (int l = 0; l < NDEPTH; ++l) {
        // ln1 folds: l==0 -> input proj (+b_in+pos); l>0 -> previous ff2 (+ffb2[l-1])
        ln_kernel<<<dim3(MROWS / 4), blk, 0, stream>>>(
            (l == 0) ? nullptr : h, spK0, spK1,
            (l == 0) ? b_in : (ffb2 + (size_t)(l - 1) * DMODEL),
            (l == 0) ? pos : nullptr, h,
            nullptr, t0h, t0l, ln1g + l * DMODEL, ln1b + l * DMODEL);
        // fused QKV -> head-major split planes (slot = part*8+head, each [M][64])
        gemm3_kernel<<<dim3(MROWS / 128, 1536 / 128, 1), blk, 0, stream>>>(
            t0h, t0l, qkvT_h + (size_t)l * 1536 * DMODEL, qkvT_l + (size_t)l * 1536 * DMODEL,
            nullptr, qkvh, qkvl, nullptr, nullptr, nullptr, MROWS, 1536, DMODEL, 0,
            nullptr, nullptr, 0, 1);
        vtrans_kernel<<<dim3(8, 8, 32), blk, 0, stream>>>(qkvh, qkvl, VTh, VTl);
        attn_flash_kernel<<<dim3(1024), blk, 0, stream>>>(
            qkvh, qkvl, VTh, VTl, obh, obl);
        // wo: split-K=2 (reduced + residual inside ln2)
        gemm3_kernel<<<dim3(MROWS / 128, DMODEL / 128, 2), blk, 0, stream>>>(
            obh, obl, woT_h + (size_t)l * S_WIN, woT_l + (size_t)l * S_WIN,
            nullptr, nullptr, nullptr, nullptr, nullptr, nullptr,
            MROWS, DMODEL, DMODEL, 0, spK0, spK1, 256, 0);
        ln_kernel<<<dim3(MROWS / 4), blk, 0, stream>>>(
            h, spK0, spK1, nullptr, nullptr, h,
            nullptr, t0h, t0l, ln2g + l * DMODEL, ln2b + l * DMODEL);
        gemm3_kernel<<<dim3(MROWS / 128, DFF / 128, 1), blk, 0, stream>>>(
            t0h, t0l, ff1T_h + (size_t)l * DFF * DMODEL, ff1T_l + (size_t)l * DFF * DMODEL,
            nullptr, fmh, fml, ffb1 + l * DFF, nullptr, nullptr, MROWS, DFF, DMODEL, 1,
            nullptr, nullptr, 0, 0);
        // ff2: split-K=2 over K=2048 (reduced + ffb2 + residual in next ln1/lnf)
        gemm3_kernel<<<dim3(MROWS / 128, DMODEL / 128, 2), blk, 0, stream>>>(
            fmh, fml, ff2T_h + (size_t)l * DFF * DMODEL, ff2T_l + (size_t)l * DFF * DMODEL,
            nullptr, nullptr, nullptr, nullptr, nullptr, nullptr,
            MROWS, DMODEL, DFF, 0, spK0, spK1, 1024, 0);
    }

    // final ln folds last ff2 (+ffb2[3]); writes fp32 t0 for the out-projection
    ln_kernel<<<dim3(MROWS / 4), blk, 0, stream>>>(
        h, spK0, spK1, ffb2 + (size_t)3 * DMODEL, nullptr, nullptr,
        t0, nullptr, nullptr, lnfg, lnfb);
    gemm_kernel<<<dim3(MROWS / 64, 1), blk, 0, stream>>>(t0, wout, zb, bout, MROWS, CBD, DMODEL);
    split_kernel<<<dim3((int)((size_t)MROWS * CBD / 256)), blk, 0, stream>>>(
        zb, zbh, zbl, MROWS * CBD);
    vq3_kernel<<<dim3(MROWS / 16), blk, 0, stream>>>(zb, zbh, zbl, cbh, cbl, cb, cbn, out);
}